// Round 10
// baseline (2062.222 us; speedup 1.0000x reference)
//
#include <hip/hip_runtime.h>

// ---------------------------------------------------------------------------
// EnhancedGraphEncoder: 4-layer GCN + BN + ReLU + skip + global mean pool
// N=100000 nodes, E=1.6M edges (+self loops), dims 128->128->128->128->64.
// hW gather buffer bf16 (compulsory-sweep bytes halved; R9: 237us/layer).
// NEW: degree-sorted node permutation (exact counting sort) + pair-of-nodes
// per 16-lane sub with joint 4+4-deep loop -> zero trip-count divergence,
// matched tails, 8 gathers in flight across 2 chains.
// BN stats/agg f32. MFMA GEMMs bf16; layer-0 converts f32 x on the fly.
// ---------------------------------------------------------------------------

typedef unsigned short u16;
typedef unsigned int u32;
typedef __attribute__((ext_vector_type(8))) short bf16x8;
typedef __attribute__((ext_vector_type(4))) float f32x4;

__device__ __forceinline__ float bflo(u32 u) { return __uint_as_float(u << 16); }
__device__ __forceinline__ float bfhi(u32 u) { return __uint_as_float(u & 0xffff0000u); }
__device__ __forceinline__ u16 f2bf(float f) {
    u32 u = __float_as_uint(f);
    u32 r = u + 0x7fffu + ((u >> 16) & 1u);   // round-to-nearest-even
    return (u16)(r >> 16);
}
__device__ __forceinline__ u32 pack2(float a, float b) {
    return (u32)f2bf(a) | ((u32)f2bf(b) << 16);
}

// unpack 8 bf16 (uint4) and FMA into two float4 accumulators
__device__ __forceinline__ void acc8(float4& r0, float4& r1, uint4 v, float w) {
    r0.x = fmaf(bflo(v.x), w, r0.x); r0.y = fmaf(bfhi(v.x), w, r0.y);
    r0.z = fmaf(bflo(v.y), w, r0.z); r0.w = fmaf(bfhi(v.y), w, r0.w);
    r1.x = fmaf(bflo(v.z), w, r1.x); r1.y = fmaf(bfhi(v.z), w, r1.y);
    r1.z = fmaf(bflo(v.w), w, r1.z); r1.w = fmaf(bfhi(v.w), w, r1.w);
}

// ------------------------- preprocessing kernels ---------------------------

__global__ void k_deg(const int* __restrict__ edst, int E, int* __restrict__ deg) {
    int e = blockIdx.x * blockDim.x + threadIdx.x;
    if (e < E) atomicAdd(&deg[edst[e]], 1);
}

__global__ void k_dinv(const int* __restrict__ deg, int n, float* __restrict__ dinv) {
    int i = blockIdx.x * blockDim.x + threadIdx.x;
    if (i < n) {
        int c = deg[i] + 1;  // + self loop
        dinv[i] = rsqrtf((float)c);
    }
}

__global__ void k_bsum(const int* __restrict__ deg, int n, int* __restrict__ bsum) {
    __shared__ int sd[256];
    int base = blockIdx.x * 1024;
    int end = base + 1024; if (end > n) end = n;
    int s = 0;
    for (int i = base + threadIdx.x; i < end; i += 256) s += deg[i] + 1;
    sd[threadIdx.x] = s;
    __syncthreads();
    for (int off = 128; off > 0; off >>= 1) {
        if (threadIdx.x < off) sd[threadIdx.x] += sd[threadIdx.x + off];
        __syncthreads();
    }
    if (threadIdx.x == 0) bsum[blockIdx.x] = sd[0];
}

__global__ void k_scanb(int* __restrict__ bsum, int B) {
    int run = 0;
    for (int i = 0; i < B; ++i) { int v = bsum[i]; bsum[i] = run; run += v; }
}

__global__ void k_offs(const int* __restrict__ deg, int n, const int* __restrict__ bsum,
                       int* __restrict__ offs) {
    __shared__ int sd[256];
    int base = blockIdx.x * 1024;
    int carry = bsum[blockIdx.x];
    for (int tile = 0; tile < 4; ++tile) {
        int i = base + tile * 256 + threadIdx.x;
        int v = (i < n) ? (deg[i] + 1) : 0;
        sd[threadIdx.x] = v;
        __syncthreads();
        int x = v;
        for (int off = 1; off < 256; off <<= 1) {
            int y = (threadIdx.x >= off) ? sd[threadIdx.x - off] : 0;
            __syncthreads();
            x += y;
            sd[threadIdx.x] = x;
            __syncthreads();
        }
        if (i < n) offs[i] = carry + x - v;
        if (i == n - 1) offs[n] = carry + x;
        carry += sd[255];
        __syncthreads();
    }
}

__global__ void k_fill_edges(const int* __restrict__ esrc, const int* __restrict__ edst, int E,
                             const float* __restrict__ dinv, const int* __restrict__ offs,
                             int* __restrict__ cursor, uint2* __restrict__ csre) {
    int e = blockIdx.x * blockDim.x + threadIdx.x;
    if (e < E) {
        int s = esrc[e], d = edst[e];
        int slot = offs[d] + atomicAdd(&cursor[d], 1);
        csre[slot] = make_uint2((u32)s, __float_as_uint(dinv[s] * dinv[d]));
    }
}

__global__ void k_fill_self(int n, const float* __restrict__ dinv, const int* __restrict__ offs,
                            int* __restrict__ cursor, uint2* __restrict__ csre) {
    int i = blockIdx.x * blockDim.x + threadIdx.x;
    if (i < n) {
        int slot = offs[i] + atomicAdd(&cursor[i], 1);
        csre[slot] = make_uint2((u32)i, __float_as_uint(dinv[i] * dinv[i]));
    }
}

// --------------- degree-sorted node permutation (counting sort) ------------

__global__ void k_hist(const int* __restrict__ deg, int n, int* __restrict__ hist) {
    int i = blockIdx.x * blockDim.x + threadIdx.x;
    if (i < n) {
        int d = deg[i]; if (d > 255) d = 255;
        atomicAdd(&hist[d], 1);
    }
}

__global__ void k_scan256(int* __restrict__ hist) {
    int run = 0;
    for (int i = 0; i < 256; ++i) { int v = hist[i]; hist[i] = run; run += v; }
}

__global__ void k_scatter(const int* __restrict__ deg, int n, const int* __restrict__ hoff,
                          int* __restrict__ hcur, int* __restrict__ perm) {
    int i = blockIdx.x * blockDim.x + threadIdx.x;
    if (i < n) {
        int d = deg[i]; if (d > 255) d = 255;
        int slot = hoff[d] + atomicAdd(&hcur[d], 1);
        perm[slot] = i;
    }
}

// batch is sorted -> per-graph counts via binary search, no atomics
__global__ void k_gcnt_bs(const int* __restrict__ batch, int n, int* __restrict__ gcnt) {
    int g = threadIdx.x;
    if (g < 128) {
        int lo0 = 0, hi0 = n;
        while (lo0 < hi0) { int m = (lo0 + hi0) >> 1; if (batch[m] < g) lo0 = m + 1; else hi0 = m; }
        int lo1 = lo0, hi1 = n;
        while (lo1 < hi1) { int m = (lo1 + hi1) >> 1; if (batch[m] < g + 1) lo1 = m + 1; else hi1 = m; }
        gcnt[g] = lo1 - lo0;
    }
}

// ------------------ weight transpose+convert: W[128][F] -> Wt[F][128] ------

template <int FOUT>
__global__ void k_wt(const float* __restrict__ W, u16* __restrict__ Wt) {
    __shared__ u16 l[128 * (FOUT + 8)];
    for (int i = threadIdx.x; i < 128 * FOUT; i += 256) {
        int k = i / FOUT, nn = i % FOUT;
        l[k * (FOUT + 8) + nn] = f2bf(W[i]);
    }
    __syncthreads();
    for (int i = threadIdx.x; i < 128 * FOUT; i += 256) {
        int nn = i >> 7, k = i & 127;
        Wt[nn * 128 + k] = l[k * (FOUT + 8) + nn];
    }
}

// ------------------------------- MFMA GEMM ---------------------------------
// O[n,FOUT](bf16) = A[n,128] @ W[128,FOUT], Wt[FOUT][128] bf16.
// A is bf16 (AF32=false) or f32 converted on the fly (AF32=true, layer 0).

template <int FOUT, bool AF32>
__global__ __launch_bounds__(256) void k_gemm_mfma(const void* __restrict__ Ap,
                                                   const u16* __restrict__ Wt,
                                                   u16* __restrict__ O, int n) {
    constexpr int NT = FOUT / 16;
    const int lane = threadIdx.x & 63;
    const int wave = threadIdx.x >> 6;
    const int fr = lane & 15;
    const int fq = lane >> 4;
    const int rowbase = blockIdx.x * 64 + wave * 16;
    const int arow = rowbase + fr;
    const bool aok = arow < n;
    const u16* ab = (const u16*)Ap + (size_t)arow * 128 + fq * 8;
    const float* af = (const float*)Ap + (size_t)arow * 128 + fq * 8;
    const u16* wp = Wt + fr * 128 + fq * 8;

    f32x4 acc[NT];
#pragma unroll
    for (int t = 0; t < NT; ++t)
#pragma unroll
        for (int q = 0; q < 4; ++q) acc[t][q] = 0.f;

#pragma unroll
    for (int kk = 0; kk < 4; ++kk) {
        bf16x8 a;
#pragma unroll
        for (int q = 0; q < 8; ++q) a[q] = 0;
        if (aok) {
            if constexpr (AF32) {
                const float4 x0 = *(const float4*)(af + kk * 32);
                const float4 x1 = *(const float4*)(af + kk * 32 + 4);
                a[0] = (short)f2bf(x0.x); a[1] = (short)f2bf(x0.y);
                a[2] = (short)f2bf(x0.z); a[3] = (short)f2bf(x0.w);
                a[4] = (short)f2bf(x1.x); a[5] = (short)f2bf(x1.y);
                a[6] = (short)f2bf(x1.z); a[7] = (short)f2bf(x1.w);
            } else {
                a = *(const bf16x8*)(ab + kk * 32);
            }
        }
#pragma unroll
        for (int t = 0; t < NT; ++t) {
            bf16x8 b = *(const bf16x8*)(wp + t * 16 * 128 + kk * 32);
            acc[t] = __builtin_amdgcn_mfma_f32_16x16x32_bf16(a, b, acc[t], 0, 0, 0);
        }
    }
#pragma unroll
    for (int i = 0; i < 4; ++i) {
        const int row = rowbase + fq * 4 + i;
        if (row < n) {
#pragma unroll
            for (int t = 0; t < NT; ++t)
                O[(size_t)row * FOUT + t * 16 + fr] = f2bf(acc[t][i]);
        }
    }
}

// ---------------------------- aggregation ----------------------------------
// agg[d,f](f32) = sum_{e: dst=d} hW[src_e, f](bf16) * norm_e  (CSR by dst)
// Each TPN-lane sub processes a PAIR of degree-matched nodes (perm sorted by
// degree): joint 4+4-deep loop -> 8 gathers in flight, 2 chains, no
// divergence. Fused BN sum/sumsq.

template <int F>
__global__ __launch_bounds__(256) void k_agg(const u16* __restrict__ hW,
                                             const uint2* __restrict__ csre,
                                             const int* __restrict__ offs,
                                             const int* __restrict__ perm,
                                             float* __restrict__ agg,
                                             float* __restrict__ stats, int n) {
    constexpr int TPN = F / 8;       // lanes per node (16 or 8)
    constexpr int PPB = 256 / TPN;   // node-pairs per block (16 or 32)
    const int lane = threadIdx.x % TPN;
    const int sub = threadIdx.x / TPN;
    const int fbase = lane * 8;
    const int npairs = (n + 1) >> 1;

    float4 ls0 = make_float4(0.f, 0.f, 0.f, 0.f);
    float4 ls1 = make_float4(0.f, 0.f, 0.f, 0.f);
    float4 lq0 = make_float4(0.f, 0.f, 0.f, 0.f);
    float4 lq1 = make_float4(0.f, 0.f, 0.f, 0.f);

    for (int pp = blockIdx.x * PPB + sub; pp < npairs; pp += gridDim.x * PPB) {
        const int nodeA = perm[2 * pp];
        const bool hasB = (2 * pp + 1) < n;
        const int nodeB = hasB ? perm[2 * pp + 1] : nodeA;
        int jA = offs[nodeA];
        const int eA = offs[nodeA + 1];
        int jB = hasB ? offs[nodeB] : 0;
        const int eB = hasB ? offs[nodeB + 1] : 0;

        float4 a0 = make_float4(0.f, 0.f, 0.f, 0.f);
        float4 a1 = make_float4(0.f, 0.f, 0.f, 0.f);
        float4 b0 = make_float4(0.f, 0.f, 0.f, 0.f);
        float4 b1 = make_float4(0.f, 0.f, 0.f, 0.f);

        // joint 4+4-deep (degrees matched by sort -> dominant path)
        while (jA + 4 <= eA && jB + 4 <= eB) {
            const uint2 xA0 = csre[jA + 0], xA1 = csre[jA + 1];
            const uint2 xA2 = csre[jA + 2], xA3 = csre[jA + 3];
            const uint2 xB0 = csre[jB + 0], xB1 = csre[jB + 1];
            const uint2 xB2 = csre[jB + 2], xB3 = csre[jB + 3];
            const uint4 vA0 = *(const uint4*)&hW[(size_t)xA0.x * F + fbase];
            const uint4 vA1 = *(const uint4*)&hW[(size_t)xA1.x * F + fbase];
            const uint4 vA2 = *(const uint4*)&hW[(size_t)xA2.x * F + fbase];
            const uint4 vA3 = *(const uint4*)&hW[(size_t)xA3.x * F + fbase];
            const uint4 vB0 = *(const uint4*)&hW[(size_t)xB0.x * F + fbase];
            const uint4 vB1 = *(const uint4*)&hW[(size_t)xB1.x * F + fbase];
            const uint4 vB2 = *(const uint4*)&hW[(size_t)xB2.x * F + fbase];
            const uint4 vB3 = *(const uint4*)&hW[(size_t)xB3.x * F + fbase];
            acc8(a0, a1, vA0, __uint_as_float(xA0.y));
            acc8(a0, a1, vA1, __uint_as_float(xA1.y));
            acc8(a0, a1, vA2, __uint_as_float(xA2.y));
            acc8(a0, a1, vA3, __uint_as_float(xA3.y));
            acc8(b0, b1, vB0, __uint_as_float(xB0.y));
            acc8(b0, b1, vB1, __uint_as_float(xB1.y));
            acc8(b0, b1, vB2, __uint_as_float(xB2.y));
            acc8(b0, b1, vB3, __uint_as_float(xB3.y));
            jA += 4; jB += 4;
        }
        while (jA + 4 <= eA) {
            const uint2 x0 = csre[jA + 0], x1 = csre[jA + 1];
            const uint2 x2 = csre[jA + 2], x3 = csre[jA + 3];
            const uint4 v0 = *(const uint4*)&hW[(size_t)x0.x * F + fbase];
            const uint4 v1 = *(const uint4*)&hW[(size_t)x1.x * F + fbase];
            const uint4 v2 = *(const uint4*)&hW[(size_t)x2.x * F + fbase];
            const uint4 v3 = *(const uint4*)&hW[(size_t)x3.x * F + fbase];
            acc8(a0, a1, v0, __uint_as_float(x0.y));
            acc8(a0, a1, v1, __uint_as_float(x1.y));
            acc8(a0, a1, v2, __uint_as_float(x2.y));
            acc8(a0, a1, v3, __uint_as_float(x3.y));
            jA += 4;
        }
        while (jB + 4 <= eB) {
            const uint2 x0 = csre[jB + 0], x1 = csre[jB + 1];
            const uint2 x2 = csre[jB + 2], x3 = csre[jB + 3];
            const uint4 v0 = *(const uint4*)&hW[(size_t)x0.x * F + fbase];
            const uint4 v1 = *(const uint4*)&hW[(size_t)x1.x * F + fbase];
            const uint4 v2 = *(const uint4*)&hW[(size_t)x2.x * F + fbase];
            const uint4 v3 = *(const uint4*)&hW[(size_t)x3.x * F + fbase];
            acc8(b0, b1, v0, __uint_as_float(x0.y));
            acc8(b0, b1, v1, __uint_as_float(x1.y));
            acc8(b0, b1, v2, __uint_as_float(x2.y));
            acc8(b0, b1, v3, __uint_as_float(x3.y));
            jB += 4;
        }
        for (; jA < eA; ++jA) {
            const uint2 x0 = csre[jA];
            const uint4 v0 = *(const uint4*)&hW[(size_t)x0.x * F + fbase];
            acc8(a0, a1, v0, __uint_as_float(x0.y));
        }
        for (; jB < eB; ++jB) {
            const uint2 x0 = csre[jB];
            const uint4 v0 = *(const uint4*)&hW[(size_t)x0.x * F + fbase];
            acc8(b0, b1, v0, __uint_as_float(x0.y));
        }

        *(float4*)&agg[(size_t)nodeA * F + fbase] = a0;
        *(float4*)&agg[(size_t)nodeA * F + fbase + 4] = a1;
        ls0.x += a0.x; ls0.y += a0.y; ls0.z += a0.z; ls0.w += a0.w;
        ls1.x += a1.x; ls1.y += a1.y; ls1.z += a1.z; ls1.w += a1.w;
        lq0.x = fmaf(a0.x, a0.x, lq0.x); lq0.y = fmaf(a0.y, a0.y, lq0.y);
        lq0.z = fmaf(a0.z, a0.z, lq0.z); lq0.w = fmaf(a0.w, a0.w, lq0.w);
        lq1.x = fmaf(a1.x, a1.x, lq1.x); lq1.y = fmaf(a1.y, a1.y, lq1.y);
        lq1.z = fmaf(a1.z, a1.z, lq1.z); lq1.w = fmaf(a1.w, a1.w, lq1.w);
        if (hasB) {
            *(float4*)&agg[(size_t)nodeB * F + fbase] = b0;
            *(float4*)&agg[(size_t)nodeB * F + fbase + 4] = b1;
            ls0.x += b0.x; ls0.y += b0.y; ls0.z += b0.z; ls0.w += b0.w;
            ls1.x += b1.x; ls1.y += b1.y; ls1.z += b1.z; ls1.w += b1.w;
            lq0.x = fmaf(b0.x, b0.x, lq0.x); lq0.y = fmaf(b0.y, b0.y, lq0.y);
            lq0.z = fmaf(b0.z, b0.z, lq0.z); lq0.w = fmaf(b0.w, b0.w, lq0.w);
            lq1.x = fmaf(b1.x, b1.x, lq1.x); lq1.y = fmaf(b1.y, b1.y, lq1.y);
            lq1.z = fmaf(b1.z, b1.z, lq1.z); lq1.w = fmaf(b1.w, b1.w, lq1.w);
        }
    }

    // reduce stats: shuffle within wave, LDS across waves
#pragma unroll
    for (int m = TPN; m < 64; m <<= 1) {
        ls0.x += __shfl_xor(ls0.x, m); ls0.y += __shfl_xor(ls0.y, m);
        ls0.z += __shfl_xor(ls0.z, m); ls0.w += __shfl_xor(ls0.w, m);
        ls1.x += __shfl_xor(ls1.x, m); ls1.y += __shfl_xor(ls1.y, m);
        ls1.z += __shfl_xor(ls1.z, m); ls1.w += __shfl_xor(ls1.w, m);
        lq0.x += __shfl_xor(lq0.x, m); lq0.y += __shfl_xor(lq0.y, m);
        lq0.z += __shfl_xor(lq0.z, m); lq0.w += __shfl_xor(lq0.w, m);
        lq1.x += __shfl_xor(lq1.x, m); lq1.y += __shfl_xor(lq1.y, m);
        lq1.z += __shfl_xor(lq1.z, m); lq1.w += __shfl_xor(lq1.w, m);
    }
    __shared__ float4 sred[2][4][TPN * 2];
    const int w = threadIdx.x >> 6;
    const int l64 = threadIdx.x & 63;
    if (l64 < TPN) {
        sred[0][w][l64 * 2 + 0] = ls0;
        sred[0][w][l64 * 2 + 1] = ls1;
        sred[1][w][l64 * 2 + 0] = lq0;
        sred[1][w][l64 * 2 + 1] = lq1;
    }
    __syncthreads();
    if (threadIdx.x < TPN * 2) {
        float4 a = sred[0][0][threadIdx.x];
        float4 b = sred[1][0][threadIdx.x];
#pragma unroll
        for (int k = 1; k < 4; ++k) {
            const float4 ta = sred[0][k][threadIdx.x];
            const float4 tb = sred[1][k][threadIdx.x];
            a.x += ta.x; a.y += ta.y; a.z += ta.z; a.w += ta.w;
            b.x += tb.x; b.y += tb.y; b.z += tb.z; b.w += tb.w;
        }
        const int f0 = threadIdx.x * 4;
        atomicAdd(&stats[f0 + 0], a.x);
        atomicAdd(&stats[f0 + 1], a.y);
        atomicAdd(&stats[f0 + 2], a.z);
        atomicAdd(&stats[f0 + 3], a.w);
        atomicAdd(&stats[F + f0 + 0], b.x);
        atomicAdd(&stats[F + f0 + 1], b.y);
        atomicAdd(&stats[F + f0 + 2], b.z);
        atomicAdd(&stats[F + f0 + 3], b.w);
    }
}

// -------------------------- BN coef + apply --------------------------------

__global__ void k_coef(const float* __restrict__ stats, const float* __restrict__ g,
                       const float* __restrict__ be, float* __restrict__ coef, int F,
                       float inv_n) {
    int f = threadIdx.x;
    if (f < F) {
        float mean = stats[f] * inv_n;
        float var = stats[F + f] * inv_n - mean * mean;
        var = fmaxf(var, 0.f);
        float sc = g[f] * rsqrtf(var + 1e-5f);
        coef[f] = sc;
        coef[F + f] = be[f] - mean * sc;
    }
}

// h(bf16) = [relu](scale*agg + shift) [+ sw*prev(bf16)]   F = 128
template <bool RELU, bool SKIP>
__global__ __launch_bounds__(256) void k_bnapply(const float* __restrict__ aggf,
                                                 const u16* __restrict__ prev,
                                                 const float* __restrict__ swp,
                                                 const float* __restrict__ coef,
                                                 u16* __restrict__ out, int n8) {
    float sw = 0.f;
    if constexpr (SKIP) sw = *swp;
    const int tid0 = blockIdx.x * 256 + threadIdx.x;
    const int foff = (tid0 * 8) & 127;   // stride (grid*2048) % 128 == 0
    const float4 sc0 = *(const float4*)&coef[foff];
    const float4 sc1 = *(const float4*)&coef[foff + 4];
    const float4 sh0 = *(const float4*)&coef[128 + foff];
    const float4 sh1 = *(const float4*)&coef[128 + foff + 4];
    for (int i = tid0; i < n8; i += gridDim.x * 256) {
        const float4 v0 = *(const float4*)&aggf[(size_t)i * 8];
        const float4 v1 = *(const float4*)&aggf[(size_t)i * 8 + 4];
        float r[8];
        r[0] = fmaf(v0.x, sc0.x, sh0.x);
        r[1] = fmaf(v0.y, sc0.y, sh0.y);
        r[2] = fmaf(v0.z, sc0.z, sh0.z);
        r[3] = fmaf(v0.w, sc0.w, sh0.w);
        r[4] = fmaf(v1.x, sc1.x, sh1.x);
        r[5] = fmaf(v1.y, sc1.y, sh1.y);
        r[6] = fmaf(v1.z, sc1.z, sh1.z);
        r[7] = fmaf(v1.w, sc1.w, sh1.w);
        if constexpr (RELU) {
#pragma unroll
            for (int q = 0; q < 8; ++q) r[q] = fmaxf(r[q], 0.f);
        }
        if constexpr (SKIP) {
            const uint4 pv = *(const uint4*)&prev[(size_t)i * 8];
            r[0] = fmaf(sw, bflo(pv.x), r[0]); r[1] = fmaf(sw, bfhi(pv.x), r[1]);
            r[2] = fmaf(sw, bflo(pv.y), r[2]); r[3] = fmaf(sw, bfhi(pv.y), r[3]);
            r[4] = fmaf(sw, bflo(pv.z), r[4]); r[5] = fmaf(sw, bfhi(pv.z), r[5]);
            r[6] = fmaf(sw, bflo(pv.w), r[6]); r[7] = fmaf(sw, bfhi(pv.w), r[7]);
        }
        uint4 o;
        o.x = pack2(r[0], r[1]);
        o.y = pack2(r[2], r[3]);
        o.z = pack2(r[4], r[5]);
        o.w = pack2(r[6], r[7]);
        *(uint4*)&out[(size_t)i * 8] = o;
    }
}

// ----------------------- layer-3 BN + mean pool -----------------------------

__global__ __launch_bounds__(256) void k_bnpool(const float* __restrict__ C,
                                                const int* __restrict__ batch,
                                                const float* __restrict__ coef,
                                                float* __restrict__ out, int n,
                                                int chunk) {
    __shared__ float pool[128 * 64];
    for (int i = threadIdx.x; i < 128 * 64; i += 256) pool[i] = 0.f;
    __syncthreads();
    const int f = threadIdx.x & 63;
    const int sub = threadIdx.x >> 6;
    const float sc = coef[f];
    const float sh = coef[64 + f];
    const int lo = blockIdx.x * chunk;
    int hi = lo + chunk; if (hi > n) hi = n;
    for (int node = lo + sub; node < hi; node += 4) {
        float v = fmaf(sc, C[(size_t)node * 64 + f], sh);
        int g = batch[node];
        atomicAdd(&pool[g * 64 + f], v);
    }
    __syncthreads();
    for (int i = threadIdx.x; i < 128 * 64; i += 256) {
        float v = pool[i];
        if (v != 0.f) atomicAdd(&out[i], v);
    }
}

__global__ void k_div(float* __restrict__ out, const int* __restrict__ gcnt, int total) {
    int i = blockIdx.x * blockDim.x + threadIdx.x;
    if (i < total) {
        int g = i >> 6;
        int c = gcnt[g];
        if (c < 1) c = 1;
        out[i] = out[i] / (float)c;
    }
}

// ------------------------------ launcher ------------------------------------

static inline size_t align256(size_t x) { return (x + 255) & ~(size_t)255; }

extern "C" void kernel_launch(void* const* d_in, const int* in_sizes, int n_in,
                              void* d_out, int out_size, void* d_ws, size_t ws_size,
                              hipStream_t stream) {
    const float* x    = (const float*)d_in[0];
    const int* ei     = (const int*)d_in[1];
    const int* batch  = (const int*)d_in[2];
    const float* W0   = (const float*)d_in[3];
    const float* g0   = (const float*)d_in[5];
    const float* be0  = (const float*)d_in[6];
    const float* W1   = (const float*)d_in[7];
    const float* g1   = (const float*)d_in[9];
    const float* be1  = (const float*)d_in[10];
    const float* W2   = (const float*)d_in[11];
    const float* g2   = (const float*)d_in[13];
    const float* be2  = (const float*)d_in[14];
    const float* W3   = (const float*)d_in[15];
    const float* g3   = (const float*)d_in[17];
    const float* be3  = (const float*)d_in[18];
    const float* swp  = (const float*)d_in[19];

    const int N = in_sizes[0] / 128;
    const int E = in_sizes[1] / 2;
    const int T = E + N;
    const int* esrc = ei;
    const int* edst = ei + E;

    char* p = (char*)d_ws;
    auto carve = [&](size_t bytes) -> char* {
        char* r = p;
        p += align256(bytes);
        return r;
    };
    int*   deg    = (int*)carve((size_t)N * 4);
    float* dinv   = (float*)carve((size_t)N * 4);
    int*   offs   = (int*)carve((size_t)(N + 1) * 4);
    int*   cursor = (int*)carve((size_t)N * 4);
    int*   bsum   = (int*)carve(256 * 4);
    int*   hist   = (int*)carve(256 * 4);
    int*   hcur   = (int*)carve(256 * 4);
    int*   perm   = (int*)carve((size_t)N * 4);
    uint2* csre   = (uint2*)carve((size_t)T * 8);
    float* stats  = (float*)carve(4 * 256 * 4);
    float* coef   = (float*)carve(4 * 256 * 4);
    int*   gcnt   = (int*)carve(128 * 4);
    u16*   Wt0    = (u16*)carve(128 * 128 * 2);
    u16*   Wt1    = (u16*)carve(128 * 128 * 2);
    u16*   Wt2    = (u16*)carve(128 * 128 * 2);
    u16*   Wt3    = (u16*)carve(64 * 128 * 2);
    u16*   hb0    = (u16*)carve((size_t)N * 128 * 2);
    u16*   hb1    = (u16*)carve((size_t)N * 128 * 2);
    u16*   hWb    = (u16*)carve((size_t)N * 128 * 2);
    float* aggf   = (float*)carve((size_t)N * 128 * 4);

    hipMemsetAsync(deg, 0, (size_t)N * 4, stream);
    hipMemsetAsync(cursor, 0, (size_t)N * 4, stream);
    hipMemsetAsync(hist, 0, 256 * 4, stream);
    hipMemsetAsync(hcur, 0, 256 * 4, stream);
    hipMemsetAsync(stats, 0, 4 * 256 * 4, stream);
    hipMemsetAsync(d_out, 0, (size_t)out_size * 4, stream);

    // graph preprocessing
    const int EB = (E + 255) / 256;
    const int NB = (N + 255) / 256;
    const int B = (N + 1023) / 1024;
    k_deg<<<EB, 256, 0, stream>>>(edst, E, deg);
    k_dinv<<<NB, 256, 0, stream>>>(deg, N, dinv);
    k_bsum<<<B, 256, 0, stream>>>(deg, N, bsum);
    k_scanb<<<1, 1, 0, stream>>>(bsum, B);
    k_offs<<<B, 256, 0, stream>>>(deg, N, bsum, offs);
    k_fill_edges<<<EB, 256, 0, stream>>>(esrc, edst, E, dinv, offs, cursor, csre);
    k_fill_self<<<NB, 256, 0, stream>>>(N, dinv, offs, cursor, csre);
    // degree-sorted permutation
    k_hist<<<NB, 256, 0, stream>>>(deg, N, hist);
    k_scan256<<<1, 1, 0, stream>>>(hist);
    k_scatter<<<NB, 256, 0, stream>>>(deg, N, hist, hcur, perm);
    k_gcnt_bs<<<1, 128, 0, stream>>>(batch, N, gcnt);

    // weights -> bf16 transposed
    k_wt<128><<<1, 256, 0, stream>>>(W0, Wt0);
    k_wt<128><<<1, 256, 0, stream>>>(W1, Wt1);
    k_wt<128><<<1, 256, 0, stream>>>(W2, Wt2);
    k_wt<64><<<1, 256, 0, stream>>>(W3, Wt3);

    const float inv_n = 1.0f / (float)N;
    const int gemm_grid = (N + 63) / 64;
    const int n8 = N * 16;
    const int chunk = (N + 255) / 256;
    const int npairs = (N + 1) / 2;
    const int agg_grid128 = (npairs + 15) / 16;
    const int agg_grid64 = (npairs + 31) / 32;

    // layer 0: x @ W0 (f32 in, cvt fused) -> agg -> BN+ReLU -> hb1
    k_gemm_mfma<128, true><<<gemm_grid, 256, 0, stream>>>((const void*)x, Wt0, hWb, N);
    k_agg<128><<<agg_grid128, 256, 0, stream>>>(hWb, csre, offs, perm, aggf, stats + 0, N);
    k_coef<<<1, 128, 0, stream>>>(stats + 0, g0, be0, coef + 0, 128, inv_n);
    k_bnapply<true, false><<<2048, 256, 0, stream>>>(aggf, nullptr, nullptr, coef + 0,
                                                     hb1, n8);
    // layer 1: hb1 @ W1 -> agg -> BN+ReLU + 0.1*hb1 -> hb0
    k_gemm_mfma<128, false><<<gemm_grid, 256, 0, stream>>>((const void*)hb1, Wt1, hWb, N);
    k_agg<128><<<agg_grid128, 256, 0, stream>>>(hWb, csre, offs, perm, aggf, stats + 256, N);
    k_coef<<<1, 128, 0, stream>>>(stats + 256, g1, be1, coef + 256, 128, inv_n);
    k_bnapply<true, true><<<2048, 256, 0, stream>>>(aggf, hb1, swp, coef + 256, hb0, n8);
    // layer 2: hb0 @ W2 -> agg -> BN+ReLU + 0.1*hb0 -> hb1
    k_gemm_mfma<128, false><<<gemm_grid, 256, 0, stream>>>((const void*)hb0, Wt2, hWb, N);
    k_agg<128><<<agg_grid128, 256, 0, stream>>>(hWb, csre, offs, perm, aggf, stats + 512, N);
    k_coef<<<1, 128, 0, stream>>>(stats + 512, g2, be2, coef + 512, 128, inv_n);
    k_bnapply<true, true><<<2048, 256, 0, stream>>>(aggf, hb0, swp, coef + 512, hb1, n8);
    // layer 3: hb1 @ W3 (128->64) -> agg -> BN -> mean pool
    k_gemm_mfma<64, false><<<gemm_grid, 256, 0, stream>>>((const void*)hb1, Wt3, hWb, N);
    k_agg<64><<<agg_grid64, 256, 0, stream>>>(hWb, csre, offs, perm, aggf, stats + 768, N);
    k_coef<<<1, 64, 0, stream>>>(stats + 768, g3, be3, coef + 768, 64, inv_n);
    k_bnpool<<<256, 256, 0, stream>>>(aggf, batch, coef + 768, (float*)d_out, N, chunk);
    k_div<<<(out_size + 255) / 256, 256, 0, stream>>>((float*)d_out, gcnt, out_size);
}

// Round 11
// 1341.819 us; speedup vs baseline: 1.5369x; 1.5369x over previous
//
#include <hip/hip_runtime.h>

// ---------------------------------------------------------------------------
// EnhancedGraphEncoder: 4-layer GCN + BN + ReLU + skip + global mean pool
// N=100000 nodes, E=1.6M edges (+self loops), dims 128->128->128->128->64.
// hW gather buffer bf16 (R9: 237us/layer, FETCH at 8-XCD compulsory floor).
// R10's degree-sort pairing REGRESSED (scattered writes) -> reverted to R9 agg.
// NEW: BN+ReLU+skip fused into the next GEMM's A-operand (3 bnapply passes
// deleted); k_agg stores aggf non-temporally (don't evict hW from L2).
// ---------------------------------------------------------------------------

typedef unsigned short u16;
typedef unsigned int u32;
typedef __attribute__((ext_vector_type(8))) short bf16x8;
typedef __attribute__((ext_vector_type(4))) float f32x4;

__device__ __forceinline__ float bflo(u32 u) { return __uint_as_float(u << 16); }
__device__ __forceinline__ float bfhi(u32 u) { return __uint_as_float(u & 0xffff0000u); }
__device__ __forceinline__ u16 f2bf(float f) {
    u32 u = __float_as_uint(f);
    u32 r = u + 0x7fffu + ((u >> 16) & 1u);   // round-to-nearest-even
    return (u16)(r >> 16);
}
__device__ __forceinline__ u32 pack2(float a, float b) {
    return (u32)f2bf(a) | ((u32)f2bf(b) << 16);
}

// ------------------------- preprocessing kernels ---------------------------

__global__ void k_deg(const int* __restrict__ edst, int E, int* __restrict__ deg) {
    int e = blockIdx.x * blockDim.x + threadIdx.x;
    if (e < E) atomicAdd(&deg[edst[e]], 1);
}

__global__ void k_dinv(const int* __restrict__ deg, int n, float* __restrict__ dinv) {
    int i = blockIdx.x * blockDim.x + threadIdx.x;
    if (i < n) {
        int c = deg[i] + 1;  // + self loop
        dinv[i] = rsqrtf((float)c);
    }
}

__global__ void k_bsum(const int* __restrict__ deg, int n, int* __restrict__ bsum) {
    __shared__ int sd[256];
    int base = blockIdx.x * 1024;
    int end = base + 1024; if (end > n) end = n;
    int s = 0;
    for (int i = base + threadIdx.x; i < end; i += 256) s += deg[i] + 1;
    sd[threadIdx.x] = s;
    __syncthreads();
    for (int off = 128; off > 0; off >>= 1) {
        if (threadIdx.x < off) sd[threadIdx.x] += sd[threadIdx.x + off];
        __syncthreads();
    }
    if (threadIdx.x == 0) bsum[blockIdx.x] = sd[0];
}

__global__ void k_scanb(int* __restrict__ bsum, int B) {
    int run = 0;
    for (int i = 0; i < B; ++i) { int v = bsum[i]; bsum[i] = run; run += v; }
}

__global__ void k_offs(const int* __restrict__ deg, int n, const int* __restrict__ bsum,
                       int* __restrict__ offs) {
    __shared__ int sd[256];
    int base = blockIdx.x * 1024;
    int carry = bsum[blockIdx.x];
    for (int tile = 0; tile < 4; ++tile) {
        int i = base + tile * 256 + threadIdx.x;
        int v = (i < n) ? (deg[i] + 1) : 0;
        sd[threadIdx.x] = v;
        __syncthreads();
        int x = v;
        for (int off = 1; off < 256; off <<= 1) {
            int y = (threadIdx.x >= off) ? sd[threadIdx.x - off] : 0;
            __syncthreads();
            x += y;
            sd[threadIdx.x] = x;
            __syncthreads();
        }
        if (i < n) offs[i] = carry + x - v;
        if (i == n - 1) offs[n] = carry + x;
        carry += sd[255];
        __syncthreads();
    }
}

__global__ void k_fill_edges(const int* __restrict__ esrc, const int* __restrict__ edst, int E,
                             const float* __restrict__ dinv, const int* __restrict__ offs,
                             int* __restrict__ cursor, uint2* __restrict__ csre) {
    int e = blockIdx.x * blockDim.x + threadIdx.x;
    if (e < E) {
        int s = esrc[e], d = edst[e];
        int slot = offs[d] + atomicAdd(&cursor[d], 1);
        csre[slot] = make_uint2((u32)s, __float_as_uint(dinv[s] * dinv[d]));
    }
}

__global__ void k_fill_self(int n, const float* __restrict__ dinv, const int* __restrict__ offs,
                            int* __restrict__ cursor, uint2* __restrict__ csre) {
    int i = blockIdx.x * blockDim.x + threadIdx.x;
    if (i < n) {
        int slot = offs[i] + atomicAdd(&cursor[i], 1);
        csre[slot] = make_uint2((u32)i, __float_as_uint(dinv[i] * dinv[i]));
    }
}

// batch is sorted -> per-graph counts via binary search, no atomics
__global__ void k_gcnt_bs(const int* __restrict__ batch, int n, int* __restrict__ gcnt) {
    int g = threadIdx.x;
    if (g < 128) {
        int lo0 = 0, hi0 = n;
        while (lo0 < hi0) { int m = (lo0 + hi0) >> 1; if (batch[m] < g) lo0 = m + 1; else hi0 = m; }
        int lo1 = lo0, hi1 = n;
        while (lo1 < hi1) { int m = (lo1 + hi1) >> 1; if (batch[m] < g + 1) lo1 = m + 1; else hi1 = m; }
        gcnt[g] = lo1 - lo0;
    }
}

// ------------------ weight transpose+convert: W[128][F] -> Wt[F][128] ------

template <int FOUT>
__global__ void k_wt(const float* __restrict__ W, u16* __restrict__ Wt) {
    __shared__ u16 l[128 * (FOUT + 8)];
    for (int i = threadIdx.x; i < 128 * FOUT; i += 256) {
        int k = i / FOUT, nn = i % FOUT;
        l[k * (FOUT + 8) + nn] = f2bf(W[i]);
    }
    __syncthreads();
    for (int i = threadIdx.x; i < 128 * FOUT; i += 256) {
        int nn = i >> 7, k = i & 127;
        Wt[nn * 128 + k] = l[k * (FOUT + 8) + nn];
    }
}

// ------------------------------- MFMA GEMM ---------------------------------
// O[n,FOUT](bf16) = A[n,128] @ W[128,FOUT], Wt[FOUT][128] bf16.
// MODE 0: A = bf16 buffer.
// MODE 1: A = f32 x, converted on the fly (layer 0).
// MODE 2: A = relu(aggf*sc+sh)      (fused BN, no skip; layer-0 epilogue)
// MODE 3: A = relu(aggf*sc+sh) + sw*hprev   (fused BN+skip)
// STOREH: additionally materialize A (bf16) to hout (needed as later skip src).

template <int FOUT, int MODE, bool STOREH>
__global__ __launch_bounds__(256) void k_gemm_mfma(const void* __restrict__ Ap,
                                                   const u16* __restrict__ hprev,
                                                   const float* __restrict__ coef,
                                                   const float* __restrict__ swp,
                                                   const u16* __restrict__ Wt,
                                                   u16* __restrict__ hout,
                                                   u16* __restrict__ O, int n) {
    constexpr int NT = FOUT / 16;
    const int lane = threadIdx.x & 63;
    const int wave = threadIdx.x >> 6;
    const int fr = lane & 15;
    const int fq = lane >> 4;
    const int rowbase = blockIdx.x * 64 + wave * 16;
    const int arow = rowbase + fr;
    const bool aok = arow < n;
    const u16* ab = (const u16*)Ap + (size_t)arow * 128 + fq * 8;
    const float* af = (const float*)Ap + (size_t)arow * 128 + fq * 8;
    const u16* hp = (MODE == 3) ? hprev + (size_t)arow * 128 + fq * 8 : nullptr;
    const u16* wp = Wt + fr * 128 + fq * 8;
    float sw = 0.f;
    if constexpr (MODE == 3) sw = *swp;

    f32x4 acc[NT];
#pragma unroll
    for (int t = 0; t < NT; ++t)
#pragma unroll
        for (int q = 0; q < 4; ++q) acc[t][q] = 0.f;

#pragma unroll
    for (int kk = 0; kk < 4; ++kk) {
        bf16x8 a;
#pragma unroll
        for (int q = 0; q < 8; ++q) a[q] = 0;
        if (aok) {
            if constexpr (MODE == 0) {
                a = *(const bf16x8*)(ab + kk * 32);
            } else if constexpr (MODE == 1) {
                const float4 x0 = *(const float4*)(af + kk * 32);
                const float4 x1 = *(const float4*)(af + kk * 32 + 4);
                a[0] = (short)f2bf(x0.x); a[1] = (short)f2bf(x0.y);
                a[2] = (short)f2bf(x0.z); a[3] = (short)f2bf(x0.w);
                a[4] = (short)f2bf(x1.x); a[5] = (short)f2bf(x1.y);
                a[6] = (short)f2bf(x1.z); a[7] = (short)f2bf(x1.w);
            } else {
                const int k0 = kk * 32 + fq * 8;
                const float4 v0 = *(const float4*)(af + kk * 32);
                const float4 v1 = *(const float4*)(af + kk * 32 + 4);
                const float4 sc0 = *(const float4*)&coef[k0];
                const float4 sc1 = *(const float4*)&coef[k0 + 4];
                const float4 sh0 = *(const float4*)&coef[128 + k0];
                const float4 sh1 = *(const float4*)&coef[128 + k0 + 4];
                float r[8];
                r[0] = fmaxf(fmaf(v0.x, sc0.x, sh0.x), 0.f);
                r[1] = fmaxf(fmaf(v0.y, sc0.y, sh0.y), 0.f);
                r[2] = fmaxf(fmaf(v0.z, sc0.z, sh0.z), 0.f);
                r[3] = fmaxf(fmaf(v0.w, sc0.w, sh0.w), 0.f);
                r[4] = fmaxf(fmaf(v1.x, sc1.x, sh1.x), 0.f);
                r[5] = fmaxf(fmaf(v1.y, sc1.y, sh1.y), 0.f);
                r[6] = fmaxf(fmaf(v1.z, sc1.z, sh1.z), 0.f);
                r[7] = fmaxf(fmaf(v1.w, sc1.w, sh1.w), 0.f);
                if constexpr (MODE == 3) {
                    const uint4 pv = *(const uint4*)(hp + kk * 32);
                    r[0] = fmaf(sw, bflo(pv.x), r[0]); r[1] = fmaf(sw, bfhi(pv.x), r[1]);
                    r[2] = fmaf(sw, bflo(pv.y), r[2]); r[3] = fmaf(sw, bfhi(pv.y), r[3]);
                    r[4] = fmaf(sw, bflo(pv.z), r[4]); r[5] = fmaf(sw, bfhi(pv.z), r[5]);
                    r[6] = fmaf(sw, bflo(pv.w), r[6]); r[7] = fmaf(sw, bfhi(pv.w), r[7]);
                }
                uint4 o;
                o.x = pack2(r[0], r[1]);
                o.y = pack2(r[2], r[3]);
                o.z = pack2(r[4], r[5]);
                o.w = pack2(r[6], r[7]);
                a = *(const bf16x8*)&o;
                if constexpr (STOREH)
                    *(uint4*)&hout[(size_t)arow * 128 + k0] = o;
            }
        }
#pragma unroll
        for (int t = 0; t < NT; ++t) {
            bf16x8 b = *(const bf16x8*)(wp + t * 16 * 128 + kk * 32);
            acc[t] = __builtin_amdgcn_mfma_f32_16x16x32_bf16(a, b, acc[t], 0, 0, 0);
        }
    }
#pragma unroll
    for (int i = 0; i < 4; ++i) {
        const int row = rowbase + fq * 4 + i;
        if (row < n) {
#pragma unroll
            for (int t = 0; t < NT; ++t)
                O[(size_t)row * FOUT + t * 16 + fr] = f2bf(acc[t][i]);
        }
    }
}

// ---------------------------- aggregation ----------------------------------
// agg[d,f](f32) = sum_{e: dst=d} hW[src_e, f](bf16) * norm_e  (CSR by dst)
// R9-proven kernel (237us): TPN=F/8 lanes per node, uint4 = 8 bf16 per lane,
// 8-deep edge unroll, named accumulators (no scratch). NEW: non-temporal
// stores for aggf (don't evict hW from L2). Fused BN sum/sumsq.

template <int F>
__global__ __launch_bounds__(256) void k_agg(const u16* __restrict__ hW,
                                             const uint2* __restrict__ csre,
                                             const int* __restrict__ offs,
                                             float* __restrict__ agg,
                                             float* __restrict__ stats, int n) {
    constexpr int TPN = F / 8;       // lanes per node (16 or 8)
    constexpr int NPB = 256 / TPN;   // nodes per block (16 or 32)
    const int lane = threadIdx.x % TPN;
    const int sub = threadIdx.x / TPN;
    const int fbase = lane * 8;

    float4 ls0 = make_float4(0.f, 0.f, 0.f, 0.f);
    float4 ls1 = make_float4(0.f, 0.f, 0.f, 0.f);
    float4 lq0 = make_float4(0.f, 0.f, 0.f, 0.f);
    float4 lq1 = make_float4(0.f, 0.f, 0.f, 0.f);

    for (int node = blockIdx.x * NPB + sub; node < n; node += gridDim.x * NPB) {
        const int beg = offs[node];
        const int end = offs[node + 1];
        float4 b0 = make_float4(0.f, 0.f, 0.f, 0.f);
        float4 b1 = make_float4(0.f, 0.f, 0.f, 0.f);
        float4 c0 = make_float4(0.f, 0.f, 0.f, 0.f);
        float4 c1 = make_float4(0.f, 0.f, 0.f, 0.f);
        int j = beg;
        for (; j + 8 <= end; j += 8) {
            uint2 ei[8];
#pragma unroll
            for (int q = 0; q < 8; ++q) ei[q] = csre[j + q];
            uint4 v[8];
#pragma unroll
            for (int q = 0; q < 8; ++q)
                v[q] = *(const uint4*)&hW[(size_t)ei[q].x * F + fbase];
#pragma unroll
            for (int q = 0; q < 8; ++q) {
                const float w = __uint_as_float(ei[q].y);
                const float4 lo = make_float4(bflo(v[q].x), bfhi(v[q].x),
                                              bflo(v[q].y), bfhi(v[q].y));
                const float4 hi = make_float4(bflo(v[q].z), bfhi(v[q].z),
                                              bflo(v[q].w), bfhi(v[q].w));
                if (q & 1) {
                    c0.x = fmaf(lo.x, w, c0.x); c0.y = fmaf(lo.y, w, c0.y);
                    c0.z = fmaf(lo.z, w, c0.z); c0.w = fmaf(lo.w, w, c0.w);
                    c1.x = fmaf(hi.x, w, c1.x); c1.y = fmaf(hi.y, w, c1.y);
                    c1.z = fmaf(hi.z, w, c1.z); c1.w = fmaf(hi.w, w, c1.w);
                } else {
                    b0.x = fmaf(lo.x, w, b0.x); b0.y = fmaf(lo.y, w, b0.y);
                    b0.z = fmaf(lo.z, w, b0.z); b0.w = fmaf(lo.w, w, b0.w);
                    b1.x = fmaf(hi.x, w, b1.x); b1.y = fmaf(hi.y, w, b1.y);
                    b1.z = fmaf(hi.z, w, b1.z); b1.w = fmaf(hi.w, w, b1.w);
                }
            }
        }
        for (; j < end; ++j) {
            const uint2 e0 = csre[j];
            const float w = __uint_as_float(e0.y);
            const uint4 v0 = *(const uint4*)&hW[(size_t)e0.x * F + fbase];
            b0.x = fmaf(bflo(v0.x), w, b0.x); b0.y = fmaf(bfhi(v0.x), w, b0.y);
            b0.z = fmaf(bflo(v0.y), w, b0.z); b0.w = fmaf(bfhi(v0.y), w, b0.w);
            b1.x = fmaf(bflo(v0.z), w, b1.x); b1.y = fmaf(bfhi(v0.z), w, b1.y);
            b1.z = fmaf(bflo(v0.w), w, b1.z); b1.w = fmaf(bfhi(v0.w), w, b1.w);
        }
        b0.x += c0.x; b0.y += c0.y; b0.z += c0.z; b0.w += c0.w;
        b1.x += c1.x; b1.y += c1.y; b1.z += c1.z; b1.w += c1.w;
        // non-temporal stores: agg data is not re-read by this kernel
        __builtin_nontemporal_store(*(const f32x4*)&b0,
                                    (f32x4*)&agg[(size_t)node * F + fbase]);
        __builtin_nontemporal_store(*(const f32x4*)&b1,
                                    (f32x4*)&agg[(size_t)node * F + fbase + 4]);
        ls0.x += b0.x; ls0.y += b0.y; ls0.z += b0.z; ls0.w += b0.w;
        ls1.x += b1.x; ls1.y += b1.y; ls1.z += b1.z; ls1.w += b1.w;
        lq0.x = fmaf(b0.x, b0.x, lq0.x); lq0.y = fmaf(b0.y, b0.y, lq0.y);
        lq0.z = fmaf(b0.z, b0.z, lq0.z); lq0.w = fmaf(b0.w, b0.w, lq0.w);
        lq1.x = fmaf(b1.x, b1.x, lq1.x); lq1.y = fmaf(b1.y, b1.y, lq1.y);
        lq1.z = fmaf(b1.z, b1.z, lq1.z); lq1.w = fmaf(b1.w, b1.w, lq1.w);
    }

    // reduce across the NPB sub-slots: shuffle within wave, LDS across waves
#pragma unroll
    for (int m = TPN; m < 64; m <<= 1) {
        ls0.x += __shfl_xor(ls0.x, m); ls0.y += __shfl_xor(ls0.y, m);
        ls0.z += __shfl_xor(ls0.z, m); ls0.w += __shfl_xor(ls0.w, m);
        ls1.x += __shfl_xor(ls1.x, m); ls1.y += __shfl_xor(ls1.y, m);
        ls1.z += __shfl_xor(ls1.z, m); ls1.w += __shfl_xor(ls1.w, m);
        lq0.x += __shfl_xor(lq0.x, m); lq0.y += __shfl_xor(lq0.y, m);
        lq0.z += __shfl_xor(lq0.z, m); lq0.w += __shfl_xor(lq0.w, m);
        lq1.x += __shfl_xor(lq1.x, m); lq1.y += __shfl_xor(lq1.y, m);
        lq1.z += __shfl_xor(lq1.z, m); lq1.w += __shfl_xor(lq1.w, m);
    }
    __shared__ float4 sred[2][4][TPN * 2];
    const int w = threadIdx.x >> 6;
    const int l64 = threadIdx.x & 63;
    if (l64 < TPN) {
        sred[0][w][l64 * 2 + 0] = ls0;
        sred[0][w][l64 * 2 + 1] = ls1;
        sred[1][w][l64 * 2 + 0] = lq0;
        sred[1][w][l64 * 2 + 1] = lq1;
    }
    __syncthreads();
    if (threadIdx.x < TPN * 2) {
        float4 a = sred[0][0][threadIdx.x];
        float4 b = sred[1][0][threadIdx.x];
#pragma unroll
        for (int k = 1; k < 4; ++k) {
            const float4 ta = sred[0][k][threadIdx.x];
            const float4 tb = sred[1][k][threadIdx.x];
            a.x += ta.x; a.y += ta.y; a.z += ta.z; a.w += ta.w;
            b.x += tb.x; b.y += tb.y; b.z += tb.z; b.w += tb.w;
        }
        const int f0 = threadIdx.x * 4;
        atomicAdd(&stats[f0 + 0], a.x);
        atomicAdd(&stats[f0 + 1], a.y);
        atomicAdd(&stats[f0 + 2], a.z);
        atomicAdd(&stats[f0 + 3], a.w);
        atomicAdd(&stats[F + f0 + 0], b.x);
        atomicAdd(&stats[F + f0 + 1], b.y);
        atomicAdd(&stats[F + f0 + 2], b.z);
        atomicAdd(&stats[F + f0 + 3], b.w);
    }
}

// -------------------------- BN coef ----------------------------------------

__global__ void k_coef(const float* __restrict__ stats, const float* __restrict__ g,
                       const float* __restrict__ be, float* __restrict__ coef, int F,
                       float inv_n) {
    int f = threadIdx.x;
    if (f < F) {
        float mean = stats[f] * inv_n;
        float var = stats[F + f] * inv_n - mean * mean;
        var = fmaxf(var, 0.f);
        float sc = g[f] * rsqrtf(var + 1e-5f);
        coef[f] = sc;
        coef[F + f] = be[f] - mean * sc;
    }
}

// ----------------------- layer-3 BN + mean pool -----------------------------

__global__ __launch_bounds__(256) void k_bnpool(const float* __restrict__ C,
                                                const int* __restrict__ batch,
                                                const float* __restrict__ coef,
                                                float* __restrict__ out, int n,
                                                int chunk) {
    __shared__ float pool[128 * 64];
    for (int i = threadIdx.x; i < 128 * 64; i += 256) pool[i] = 0.f;
    __syncthreads();
    const int f = threadIdx.x & 63;
    const int sub = threadIdx.x >> 6;
    const float sc = coef[f];
    const float sh = coef[64 + f];
    const int lo = blockIdx.x * chunk;
    int hi = lo + chunk; if (hi > n) hi = n;
    for (int node = lo + sub; node < hi; node += 4) {
        float v = fmaf(sc, C[(size_t)node * 64 + f], sh);
        int g = batch[node];
        atomicAdd(&pool[g * 64 + f], v);
    }
    __syncthreads();
    for (int i = threadIdx.x; i < 128 * 64; i += 256) {
        float v = pool[i];
        if (v != 0.f) atomicAdd(&out[i], v);
    }
}

__global__ void k_div(float* __restrict__ out, const int* __restrict__ gcnt, int total) {
    int i = blockIdx.x * blockDim.x + threadIdx.x;
    if (i < total) {
        int g = i >> 6;
        int c = gcnt[g];
        if (c < 1) c = 1;
        out[i] = out[i] / (float)c;
    }
}

// ------------------------------ launcher ------------------------------------

static inline size_t align256(size_t x) { return (x + 255) & ~(size_t)255; }

extern "C" void kernel_launch(void* const* d_in, const int* in_sizes, int n_in,
                              void* d_out, int out_size, void* d_ws, size_t ws_size,
                              hipStream_t stream) {
    const float* x    = (const float*)d_in[0];
    const int* ei     = (const int*)d_in[1];
    const int* batch  = (const int*)d_in[2];
    const float* W0   = (const float*)d_in[3];
    const float* g0   = (const float*)d_in[5];
    const float* be0  = (const float*)d_in[6];
    const float* W1   = (const float*)d_in[7];
    const float* g1   = (const float*)d_in[9];
    const float* be1  = (const float*)d_in[10];
    const float* W2   = (const float*)d_in[11];
    const float* g2   = (const float*)d_in[13];
    const float* be2  = (const float*)d_in[14];
    const float* W3   = (const float*)d_in[15];
    const float* g3   = (const float*)d_in[17];
    const float* be3  = (const float*)d_in[18];
    const float* swp  = (const float*)d_in[19];

    const int N = in_sizes[0] / 128;
    const int E = in_sizes[1] / 2;
    const int T = E + N;
    const int* esrc = ei;
    const int* edst = ei + E;

    char* p = (char*)d_ws;
    auto carve = [&](size_t bytes) -> char* {
        char* r = p;
        p += align256(bytes);
        return r;
    };
    int*   deg    = (int*)carve((size_t)N * 4);
    float* dinv   = (float*)carve((size_t)N * 4);
    int*   offs   = (int*)carve((size_t)(N + 1) * 4);
    int*   cursor = (int*)carve((size_t)N * 4);
    int*   bsum   = (int*)carve(256 * 4);
    uint2* csre   = (uint2*)carve((size_t)T * 8);
    float* stats  = (float*)carve(4 * 256 * 4);
    float* coef   = (float*)carve(4 * 256 * 4);
    int*   gcnt   = (int*)carve(128 * 4);
    u16*   Wt0    = (u16*)carve(128 * 128 * 2);
    u16*   Wt1    = (u16*)carve(128 * 128 * 2);
    u16*   Wt2    = (u16*)carve(128 * 128 * 2);
    u16*   Wt3    = (u16*)carve(64 * 128 * 2);
    u16*   h0     = (u16*)carve((size_t)N * 128 * 2);
    u16*   h1     = (u16*)carve((size_t)N * 128 * 2);
    u16*   hWb    = (u16*)carve((size_t)N * 128 * 2);
    float* aggf   = (float*)carve((size_t)N * 128 * 4);

    hipMemsetAsync(deg, 0, (size_t)N * 4, stream);
    hipMemsetAsync(cursor, 0, (size_t)N * 4, stream);
    hipMemsetAsync(stats, 0, 4 * 256 * 4, stream);
    hipMemsetAsync(d_out, 0, (size_t)out_size * 4, stream);

    // graph preprocessing
    const int EB = (E + 255) / 256;
    const int NB = (N + 255) / 256;
    const int B = (N + 1023) / 1024;
    k_deg<<<EB, 256, 0, stream>>>(edst, E, deg);
    k_dinv<<<NB, 256, 0, stream>>>(deg, N, dinv);
    k_bsum<<<B, 256, 0, stream>>>(deg, N, bsum);
    k_scanb<<<1, 1, 0, stream>>>(bsum, B);
    k_offs<<<B, 256, 0, stream>>>(deg, N, bsum, offs);
    k_fill_edges<<<EB, 256, 0, stream>>>(esrc, edst, E, dinv, offs, cursor, csre);
    k_fill_self<<<NB, 256, 0, stream>>>(N, dinv, offs, cursor, csre);
    k_gcnt_bs<<<1, 128, 0, stream>>>(batch, N, gcnt);

    // weights -> bf16 transposed
    k_wt<128><<<1, 256, 0, stream>>>(W0, Wt0);
    k_wt<128><<<1, 256, 0, stream>>>(W1, Wt1);
    k_wt<128><<<1, 256, 0, stream>>>(W2, Wt2);
    k_wt<64><<<1, 256, 0, stream>>>(W3, Wt3);

    const float inv_n = 1.0f / (float)N;
    const int gemm_grid = (N + 63) / 64;
    const int chunk = (N + 255) / 256;

    // layer 0: x @ W0 (f32 in, cvt fused) -> agg -> coef
    k_gemm_mfma<128, 1, false><<<gemm_grid, 256, 0, stream>>>(
        (const void*)x, nullptr, nullptr, nullptr, Wt0, nullptr, hWb, N);
    k_agg<128><<<2048, 256, 0, stream>>>(hWb, csre, offs, aggf, stats + 0, N);
    k_coef<<<1, 128, 0, stream>>>(stats + 0, g0, be0, coef + 0, 128, inv_n);
    // layer 1: GEMM fuses bnapply_0 (no skip), stores h0; -> agg -> coef
    k_gemm_mfma<128, 2, true><<<gemm_grid, 256, 0, stream>>>(
        (const void*)aggf, nullptr, coef + 0, nullptr, Wt1, h0, hWb, N);
    k_agg<128><<<2048, 256, 0, stream>>>(hWb, csre, offs, aggf, stats + 256, N);
    k_coef<<<1, 128, 0, stream>>>(stats + 256, g1, be1, coef + 256, 128, inv_n);
    // layer 2: GEMM fuses bnapply_1 (skip from h0), stores h1; -> agg -> coef
    k_gemm_mfma<128, 3, true><<<gemm_grid, 256, 0, stream>>>(
        (const void*)aggf, h0, coef + 256, swp, Wt2, h1, hWb, N);
    k_agg<128><<<2048, 256, 0, stream>>>(hWb, csre, offs, aggf, stats + 512, N);
    k_coef<<<1, 128, 0, stream>>>(stats + 512, g2, be2, coef + 512, 128, inv_n);
    // layer 3: GEMM fuses bnapply_2 (skip from h1, no store); -> agg -> coef
    k_gemm_mfma<64, 3, false><<<gemm_grid, 256, 0, stream>>>(
        (const void*)aggf, h1, coef + 512, swp, Wt3, nullptr, hWb, N);
    k_agg<64><<<2048, 256, 0, stream>>>(hWb, csre, offs, aggf, stats + 768, N);
    k_coef<<<1, 64, 0, stream>>>(stats + 768, g3, be3, coef + 768, 64, inv_n);
    // BN + mean pool
    k_bnpool<<<256, 256, 0, stream>>>(aggf, batch, coef + 768, (float*)d_out, N, chunk);
    k_div<<<(out_size + 255) / 256, 256, 0, stream>>>((float*)d_out, gcnt, out_size);
}

// Round 12
// 1080.071 us; speedup vs baseline: 1.9093x; 1.2423x over previous
//
#include <hip/hip_runtime.h>

// ---------------------------------------------------------------------------
// EnhancedGraphEncoder: 4-layer GCN + BN + ReLU + skip + global mean pool
// N=100000 nodes, E=1.6M edges (+self loops), dims 128->128->128->128->64.
// hW gather bf16 (FETCH at 8-XCD compulsory floor). NEW: BN stats evicted
// from k_agg into a streaming k_stats pass (fused coef via ticket) -> k_agg
// is pure gather, lower VGPR -> higher occupancy -> higher gather rate
// (rate~occ observed across R1-R11). BN+ReLU+skip stay fused in GEMMs.
// ---------------------------------------------------------------------------

typedef unsigned short u16;
typedef unsigned int u32;
typedef __attribute__((ext_vector_type(8))) short bf16x8;
typedef __attribute__((ext_vector_type(4))) float f32x4;

__device__ __forceinline__ float bflo(u32 u) { return __uint_as_float(u << 16); }
__device__ __forceinline__ float bfhi(u32 u) { return __uint_as_float(u & 0xffff0000u); }
__device__ __forceinline__ u16 f2bf(float f) {
    u32 u = __float_as_uint(f);
    u32 r = u + 0x7fffu + ((u >> 16) & 1u);   // round-to-nearest-even
    return (u16)(r >> 16);
}
__device__ __forceinline__ u32 pack2(float a, float b) {
    return (u32)f2bf(a) | ((u32)f2bf(b) << 16);
}

// ------------------------- preprocessing kernels ---------------------------

__global__ void k_deg(const int* __restrict__ edst, int E, int* __restrict__ deg) {
    int e = blockIdx.x * blockDim.x + threadIdx.x;
    if (e < E) atomicAdd(&deg[edst[e]], 1);
}

__global__ void k_dinv(const int* __restrict__ deg, int n, float* __restrict__ dinv) {
    int i = blockIdx.x * blockDim.x + threadIdx.x;
    if (i < n) {
        int c = deg[i] + 1;  // + self loop
        dinv[i] = rsqrtf((float)c);
    }
}

__global__ void k_bsum(const int* __restrict__ deg, int n, int* __restrict__ bsum) {
    __shared__ int sd[256];
    int base = blockIdx.x * 1024;
    int end = base + 1024; if (end > n) end = n;
    int s = 0;
    for (int i = base + threadIdx.x; i < end; i += 256) s += deg[i] + 1;
    sd[threadIdx.x] = s;
    __syncthreads();
    for (int off = 128; off > 0; off >>= 1) {
        if (threadIdx.x < off) sd[threadIdx.x] += sd[threadIdx.x + off];
        __syncthreads();
    }
    if (threadIdx.x == 0) bsum[blockIdx.x] = sd[0];
}

__global__ void k_scanb(int* __restrict__ bsum, int B) {
    int run = 0;
    for (int i = 0; i < B; ++i) { int v = bsum[i]; bsum[i] = run; run += v; }
}

__global__ void k_offs(const int* __restrict__ deg, int n, const int* __restrict__ bsum,
                       int* __restrict__ offs) {
    __shared__ int sd[256];
    int base = blockIdx.x * 1024;
    int carry = bsum[blockIdx.x];
    for (int tile = 0; tile < 4; ++tile) {
        int i = base + tile * 256 + threadIdx.x;
        int v = (i < n) ? (deg[i] + 1) : 0;
        sd[threadIdx.x] = v;
        __syncthreads();
        int x = v;
        for (int off = 1; off < 256; off <<= 1) {
            int y = (threadIdx.x >= off) ? sd[threadIdx.x - off] : 0;
            __syncthreads();
            x += y;
            sd[threadIdx.x] = x;
            __syncthreads();
        }
        if (i < n) offs[i] = carry + x - v;
        if (i == n - 1) offs[n] = carry + x;
        carry += sd[255];
        __syncthreads();
    }
}

__global__ void k_fill_edges(const int* __restrict__ esrc, const int* __restrict__ edst, int E,
                             const float* __restrict__ dinv, const int* __restrict__ offs,
                             int* __restrict__ cursor, uint2* __restrict__ csre) {
    int e = blockIdx.x * blockDim.x + threadIdx.x;
    if (e < E) {
        int s = esrc[e], d = edst[e];
        int slot = offs[d] + atomicAdd(&cursor[d], 1);
        csre[slot] = make_uint2((u32)s, __float_as_uint(dinv[s] * dinv[d]));
    }
}

__global__ void k_fill_self(int n, const float* __restrict__ dinv, const int* __restrict__ offs,
                            int* __restrict__ cursor, uint2* __restrict__ csre) {
    int i = blockIdx.x * blockDim.x + threadIdx.x;
    if (i < n) {
        int slot = offs[i] + atomicAdd(&cursor[i], 1);
        csre[slot] = make_uint2((u32)i, __float_as_uint(dinv[i] * dinv[i]));
    }
}

// batch is sorted -> per-graph counts via binary search, no atomics
__global__ void k_gcnt_bs(const int* __restrict__ batch, int n, int* __restrict__ gcnt) {
    int g = threadIdx.x;
    if (g < 128) {
        int lo0 = 0, hi0 = n;
        while (lo0 < hi0) { int m = (lo0 + hi0) >> 1; if (batch[m] < g) lo0 = m + 1; else hi0 = m; }
        int lo1 = lo0, hi1 = n;
        while (lo1 < hi1) { int m = (lo1 + hi1) >> 1; if (batch[m] < g + 1) lo1 = m + 1; else hi1 = m; }
        gcnt[g] = lo1 - lo0;
    }
}

// ------------------ weight transpose+convert: W[128][F] -> Wt[F][128] ------

template <int FOUT>
__global__ void k_wt(const float* __restrict__ W, u16* __restrict__ Wt) {
    __shared__ u16 l[128 * (FOUT + 8)];
    for (int i = threadIdx.x; i < 128 * FOUT; i += 256) {
        int k = i / FOUT, nn = i % FOUT;
        l[k * (FOUT + 8) + nn] = f2bf(W[i]);
    }
    __syncthreads();
    for (int i = threadIdx.x; i < 128 * FOUT; i += 256) {
        int nn = i >> 7, k = i & 127;
        Wt[nn * 128 + k] = l[k * (FOUT + 8) + nn];
    }
}

// ------------------------------- MFMA GEMM ---------------------------------
// O[n,FOUT](bf16) = A[n,128] @ W[128,FOUT], Wt[FOUT][128] bf16.
// MODE 1: A = f32 x, converted on the fly (layer 0).
// MODE 2: A = relu(aggf*sc+sh)      (fused BN, no skip)
// MODE 3: A = relu(aggf*sc+sh) + sw*hprev   (fused BN+skip)
// STOREH: additionally materialize A (bf16) to hout (later skip src).

template <int FOUT, int MODE, bool STOREH>
__global__ __launch_bounds__(256) void k_gemm_mfma(const void* __restrict__ Ap,
                                                   const u16* __restrict__ hprev,
                                                   const float* __restrict__ coef,
                                                   const float* __restrict__ swp,
                                                   const u16* __restrict__ Wt,
                                                   u16* __restrict__ hout,
                                                   u16* __restrict__ O, int n) {
    constexpr int NT = FOUT / 16;
    const int lane = threadIdx.x & 63;
    const int wave = threadIdx.x >> 6;
    const int fr = lane & 15;
    const int fq = lane >> 4;
    const int rowbase = blockIdx.x * 64 + wave * 16;
    const int arow = rowbase + fr;
    const bool aok = arow < n;
    const float* af = (const float*)Ap + (size_t)arow * 128 + fq * 8;
    const u16* hp = (MODE == 3) ? hprev + (size_t)arow * 128 + fq * 8 : nullptr;
    const u16* wp = Wt + fr * 128 + fq * 8;
    float sw = 0.f;
    if constexpr (MODE == 3) sw = *swp;

    f32x4 acc[NT];
#pragma unroll
    for (int t = 0; t < NT; ++t)
#pragma unroll
        for (int q = 0; q < 4; ++q) acc[t][q] = 0.f;

#pragma unroll
    for (int kk = 0; kk < 4; ++kk) {
        bf16x8 a;
#pragma unroll
        for (int q = 0; q < 8; ++q) a[q] = 0;
        if (aok) {
            if constexpr (MODE == 1) {
                const float4 x0 = *(const float4*)(af + kk * 32);
                const float4 x1 = *(const float4*)(af + kk * 32 + 4);
                a[0] = (short)f2bf(x0.x); a[1] = (short)f2bf(x0.y);
                a[2] = (short)f2bf(x0.z); a[3] = (short)f2bf(x0.w);
                a[4] = (short)f2bf(x1.x); a[5] = (short)f2bf(x1.y);
                a[6] = (short)f2bf(x1.z); a[7] = (short)f2bf(x1.w);
            } else {
                const int k0 = kk * 32 + fq * 8;
                const float4 v0 = *(const float4*)(af + kk * 32);
                const float4 v1 = *(const float4*)(af + kk * 32 + 4);
                const float4 sc0 = *(const float4*)&coef[k0];
                const float4 sc1 = *(const float4*)&coef[k0 + 4];
                const float4 sh0 = *(const float4*)&coef[128 + k0];
                const float4 sh1 = *(const float4*)&coef[128 + k0 + 4];
                float r[8];
                r[0] = fmaxf(fmaf(v0.x, sc0.x, sh0.x), 0.f);
                r[1] = fmaxf(fmaf(v0.y, sc0.y, sh0.y), 0.f);
                r[2] = fmaxf(fmaf(v0.z, sc0.z, sh0.z), 0.f);
                r[3] = fmaxf(fmaf(v0.w, sc0.w, sh0.w), 0.f);
                r[4] = fmaxf(fmaf(v1.x, sc1.x, sh1.x), 0.f);
                r[5] = fmaxf(fmaf(v1.y, sc1.y, sh1.y), 0.f);
                r[6] = fmaxf(fmaf(v1.z, sc1.z, sh1.z), 0.f);
                r[7] = fmaxf(fmaf(v1.w, sc1.w, sh1.w), 0.f);
                if constexpr (MODE == 3) {
                    const uint4 pv = *(const uint4*)(hp + kk * 32);
                    r[0] = fmaf(sw, bflo(pv.x), r[0]); r[1] = fmaf(sw, bfhi(pv.x), r[1]);
                    r[2] = fmaf(sw, bflo(pv.y), r[2]); r[3] = fmaf(sw, bfhi(pv.y), r[3]);
                    r[4] = fmaf(sw, bflo(pv.z), r[4]); r[5] = fmaf(sw, bfhi(pv.z), r[5]);
                    r[6] = fmaf(sw, bflo(pv.w), r[6]); r[7] = fmaf(sw, bfhi(pv.w), r[7]);
                }
                uint4 o;
                o.x = pack2(r[0], r[1]);
                o.y = pack2(r[2], r[3]);
                o.z = pack2(r[4], r[5]);
                o.w = pack2(r[6], r[7]);
                a = *(const bf16x8*)&o;
                if constexpr (STOREH)
                    *(uint4*)&hout[(size_t)arow * 128 + k0] = o;
            }
        }
#pragma unroll
        for (int t = 0; t < NT; ++t) {
            bf16x8 b = *(const bf16x8*)(wp + t * 16 * 128 + kk * 32);
            acc[t] = __builtin_amdgcn_mfma_f32_16x16x32_bf16(a, b, acc[t], 0, 0, 0);
        }
    }
#pragma unroll
    for (int i = 0; i < 4; ++i) {
        const int row = rowbase + fq * 4 + i;
        if (row < n) {
#pragma unroll
            for (int t = 0; t < NT; ++t)
                O[(size_t)row * FOUT + t * 16 + fr] = f2bf(acc[t][i]);
        }
    }
}

// ---------------------------- aggregation ----------------------------------
// agg[d,f](f32) = sum_{e: dst=d} hW[src_e, f](bf16) * norm_e  (CSR by dst)
// PURE gather: no BN stats (moved to k_stats) -> lower VGPR -> higher occ.
// TPN=F/8 lanes per node, uint4 = 8 bf16 per lane, 8-deep edge unroll,
// named accumulators. Non-temporal stores (aggf not re-read here).

template <int F>
__global__ __launch_bounds__(256) void k_agg(const u16* __restrict__ hW,
                                             const uint2* __restrict__ csre,
                                             const int* __restrict__ offs,
                                             float* __restrict__ agg, int n) {
    constexpr int TPN = F / 8;       // lanes per node (16 or 8)
    constexpr int NPB = 256 / TPN;   // nodes per block (16 or 32)
    const int lane = threadIdx.x % TPN;
    const int sub = threadIdx.x / TPN;
    const int fbase = lane * 8;

    for (int node = blockIdx.x * NPB + sub; node < n; node += gridDim.x * NPB) {
        const int beg = offs[node];
        const int end = offs[node + 1];
        float4 b0 = make_float4(0.f, 0.f, 0.f, 0.f);
        float4 b1 = make_float4(0.f, 0.f, 0.f, 0.f);
        float4 c0 = make_float4(0.f, 0.f, 0.f, 0.f);
        float4 c1 = make_float4(0.f, 0.f, 0.f, 0.f);
        int j = beg;
        for (; j + 8 <= end; j += 8) {
            uint2 ei[8];
#pragma unroll
            for (int q = 0; q < 8; ++q) ei[q] = csre[j + q];
            uint4 v[8];
#pragma unroll
            for (int q = 0; q < 8; ++q)
                v[q] = *(const uint4*)&hW[(size_t)ei[q].x * F + fbase];
#pragma unroll
            for (int q = 0; q < 8; ++q) {
                const float w = __uint_as_float(ei[q].y);
                if (q & 1) {
                    c0.x = fmaf(bflo(v[q].x), w, c0.x); c0.y = fmaf(bfhi(v[q].x), w, c0.y);
                    c0.z = fmaf(bflo(v[q].y), w, c0.z); c0.w = fmaf(bfhi(v[q].y), w, c0.w);
                    c1.x = fmaf(bflo(v[q].z), w, c1.x); c1.y = fmaf(bfhi(v[q].z), w, c1.y);
                    c1.z = fmaf(bflo(v[q].w), w, c1.z); c1.w = fmaf(bfhi(v[q].w), w, c1.w);
                } else {
                    b0.x = fmaf(bflo(v[q].x), w, b0.x); b0.y = fmaf(bfhi(v[q].x), w, b0.y);
                    b0.z = fmaf(bflo(v[q].y), w, b0.z); b0.w = fmaf(bfhi(v[q].y), w, b0.w);
                    b1.x = fmaf(bflo(v[q].z), w, b1.x); b1.y = fmaf(bfhi(v[q].z), w, b1.y);
                    b1.z = fmaf(bflo(v[q].w), w, b1.z); b1.w = fmaf(bfhi(v[q].w), w, b1.w);
                }
            }
        }
        for (; j < end; ++j) {
            const uint2 e0 = csre[j];
            const float w = __uint_as_float(e0.y);
            const uint4 v0 = *(const uint4*)&hW[(size_t)e0.x * F + fbase];
            b0.x = fmaf(bflo(v0.x), w, b0.x); b0.y = fmaf(bfhi(v0.x), w, b0.y);
            b0.z = fmaf(bflo(v0.y), w, b0.z); b0.w = fmaf(bfhi(v0.y), w, b0.w);
            b1.x = fmaf(bflo(v0.z), w, b1.x); b1.y = fmaf(bfhi(v0.z), w, b1.y);
            b1.z = fmaf(bflo(v0.w), w, b1.z); b1.w = fmaf(bfhi(v0.w), w, b1.w);
        }
        b0.x += c0.x; b0.y += c0.y; b0.z += c0.z; b0.w += c0.w;
        b1.x += c1.x; b1.y += c1.y; b1.z += c1.z; b1.w += c1.w;
        __builtin_nontemporal_store(*(const f32x4*)&b0,
                                    (f32x4*)&agg[(size_t)node * F + fbase]);
        __builtin_nontemporal_store(*(const f32x4*)&b1,
                                    (f32x4*)&agg[(size_t)node * F + fbase + 4]);
    }
}

// --------------------- BN stats + coef (fused, ticketed) -------------------
// Streams aggf once: per-feature sum & sumsq -> atomics into stats; the LAST
// block to finish computes coef = {scale, shift} (saves a launch per layer).

template <int F>
__global__ __launch_bounds__(256) void k_stats(const float* __restrict__ aggf,
                                               float* __restrict__ stats,
                                               int* __restrict__ ticket,
                                               const float* __restrict__ g,
                                               const float* __restrict__ be,
                                               float* __restrict__ coef,
                                               float inv_n, int n8) {
    constexpr int TPR = F / 8;
    const int tid0 = blockIdx.x * 256 + threadIdx.x;
    const int fbase = (tid0 * 8) & (F - 1);   // stride ≡ 0 (mod F)
    float s[8], q[8];
#pragma unroll
    for (int k = 0; k < 8; ++k) { s[k] = 0.f; q[k] = 0.f; }
    for (int i = tid0; i < n8; i += gridDim.x * 256) {
        const float4 v0 = *(const float4*)&aggf[(size_t)i * 8];
        const float4 v1 = *(const float4*)&aggf[(size_t)i * 8 + 4];
        s[0] += v0.x; s[1] += v0.y; s[2] += v0.z; s[3] += v0.w;
        s[4] += v1.x; s[5] += v1.y; s[6] += v1.z; s[7] += v1.w;
        q[0] = fmaf(v0.x, v0.x, q[0]); q[1] = fmaf(v0.y, v0.y, q[1]);
        q[2] = fmaf(v0.z, v0.z, q[2]); q[3] = fmaf(v0.w, v0.w, q[3]);
        q[4] = fmaf(v1.x, v1.x, q[4]); q[5] = fmaf(v1.y, v1.y, q[5]);
        q[6] = fmaf(v1.z, v1.z, q[6]); q[7] = fmaf(v1.w, v1.w, q[7]);
    }
    // reduce lanes with identical fbase (differ in bits >= log2(TPR))
#pragma unroll
    for (int m = TPR; m < 64; m <<= 1) {
#pragma unroll
        for (int k = 0; k < 8; ++k) {
            s[k] += __shfl_xor(s[k], m);
            q[k] += __shfl_xor(q[k], m);
        }
    }
    __shared__ float sred[2][4][TPR * 8];
    const int w = threadIdx.x >> 6;
    const int l64 = threadIdx.x & 63;
    if (l64 < TPR) {
#pragma unroll
        for (int k = 0; k < 8; ++k) {
            sred[0][w][l64 * 8 + k] = s[k];
            sred[1][w][l64 * 8 + k] = q[k];
        }
    }
    __syncthreads();
    if (threadIdx.x < TPR * 8) {
        float a = sred[0][0][threadIdx.x] + sred[0][1][threadIdx.x] +
                  sred[0][2][threadIdx.x] + sred[0][3][threadIdx.x];
        float b = sred[1][0][threadIdx.x] + sred[1][1][threadIdx.x] +
                  sred[1][2][threadIdx.x] + sred[1][3][threadIdx.x];
        // fbase of group base thread: ((blockIdx*256 + base)*8) & (F-1); groups
        // of TPR consecutive lanes cover features contiguously from that base.
        const int gbase = ((blockIdx.x * 256) * 8) & (F - 1);
        const int f = (gbase + threadIdx.x * 8 % F + threadIdx.x / TPR * 0 +
                       (threadIdx.x % TPR) * 8 + (threadIdx.x / TPR) * 0) & (F - 1);
        // simpler: thread t in wave w handled fbase=((blockIdx*256 + w*64 + t)*8)&(F-1)
        // after reduction, thread index tid<TPR*8 maps: feature = (tid) since
        // sred was indexed l64*8+k with l64<TPR covering F features 0..F-1
        // relative to wave-lane0's fbase; wave-lane0 fbase = ((blockIdx*256+w*64)*8)&(F-1)
        // = (blockIdx*2048)&(F-1) + ... 64*8=512 ≡ 0 mod F -> same base for all waves.
        const int fb0 = ((size_t)blockIdx.x * 256 * 8) & (F - 1);
        const int ff = (fb0 + threadIdx.x) & (F - 1);
        atomicAdd(&stats[ff], a);
        atomicAdd(&stats[F + ff], b);
    }
    __threadfence();
    __shared__ int last;
    if (threadIdx.x == 0) last = (atomicAdd(ticket, 1) == (int)gridDim.x - 1) ? 1 : 0;
    __syncthreads();
    if (last) {
        if (threadIdx.x < F) {
            const int f = threadIdx.x;
            float sum = atomicAdd(&stats[f], 0.f);        // L2-coherent read
            float ssq = atomicAdd(&stats[F + f], 0.f);
            float mean = sum * inv_n;
            float var = fmaxf(ssq * inv_n - mean * mean, 0.f);
            float sc = g[f] * rsqrtf(var + 1e-5f);
            coef[f] = sc;
            coef[F + f] = be[f] - mean * sc;
        }
    }
}

// ----------------------- layer-3 BN + mean pool -----------------------------

__global__ __launch_bounds__(256) void k_bnpool(const float* __restrict__ C,
                                                const int* __restrict__ batch,
                                                const float* __restrict__ coef,
                                                float* __restrict__ out, int n,
                                                int chunk) {
    __shared__ float pool[128 * 64];
    for (int i = threadIdx.x; i < 128 * 64; i += 256) pool[i] = 0.f;
    __syncthreads();
    const int f = threadIdx.x & 63;
    const int sub = threadIdx.x >> 6;
    const float sc = coef[f];
    const float sh = coef[64 + f];
    const int lo = blockIdx.x * chunk;
    int hi = lo + chunk; if (hi > n) hi = n;
    for (int node = lo + sub; node < hi; node += 4) {
        float v = fmaf(sc, C[(size_t)node * 64 + f], sh);
        int g = batch[node];
        atomicAdd(&pool[g * 64 + f], v);
    }
    __syncthreads();
    for (int i = threadIdx.x; i < 128 * 64; i += 256) {
        float v = pool[i];
        if (v != 0.f) atomicAdd(&out[i], v);
    }
}

__global__ void k_div(float* __restrict__ out, const int* __restrict__ gcnt, int total) {
    int i = blockIdx.x * blockDim.x + threadIdx.x;
    if (i < total) {
        int g = i >> 6;
        int c = gcnt[g];
        if (c < 1) c = 1;
        out[i] = out[i] / (float)c;
    }
}

// ------------------------------ launcher ------------------------------------

static inline size_t align256(size_t x) { return (x + 255) & ~(size_t)255; }

extern "C" void kernel_launch(void* const* d_in, const int* in_sizes, int n_in,
                              void* d_out, int out_size, void* d_ws, size_t ws_size,
                              hipStream_t stream) {
    const float* x    = (const float*)d_in[0];
    const int* ei     = (const int*)d_in[1];
    const int* batch  = (const int*)d_in[2];
    const float* W0   = (const float*)d_in[3];
    const float* g0   = (const float*)d_in[5];
    const float* be0  = (const float*)d_in[6];
    const float* W1   = (const float*)d_in[7];
    const float* g1   = (const float*)d_in[9];
    const float* be1  = (const float*)d_in[10];
    const float* W2   = (const float*)d_in[11];
    const float* g2   = (const float*)d_in[13];
    const float* be2  = (const float*)d_in[14];
    const float* W3   = (const float*)d_in[15];
    const float* g3   = (const float*)d_in[17];
    const float* be3  = (const float*)d_in[18];
    const float* swp  = (const float*)d_in[19];

    const int N = in_sizes[0] / 128;
    const int E = in_sizes[1] / 2;
    const int T = E + N;
    const int* esrc = ei;
    const int* edst = ei + E;

    char* p = (char*)d_ws;
    auto carve = [&](size_t bytes) -> char* {
        char* r = p;
        p += align256(bytes);
        return r;
    };
    int*   deg    = (int*)carve((size_t)N * 4);
    float* dinv   = (float*)carve((size_t)N * 4);
    int*   offs   = (int*)carve((size_t)(N + 1) * 4);
    int*   cursor = (int*)carve((size_t)N * 4);
    int*   bsum   = (int*)carve(256 * 4);
    uint2* csre   = (uint2*)carve((size_t)T * 8);
    float* stats  = (float*)carve(4 * 256 * 4);
    float* coef   = (float*)carve(4 * 256 * 4);
    int*   ticket = (int*)carve(4 * 4);
    int*   gcnt   = (int*)carve(128 * 4);
    u16*   Wt0    = (u16*)carve(128 * 128 * 2);
    u16*   Wt1    = (u16*)carve(128 * 128 * 2);
    u16*   Wt2    = (u16*)carve(128 * 128 * 2);
    u16*   Wt3    = (u16*)carve(64 * 128 * 2);
    u16*   h0     = (u16*)carve((size_t)N * 128 * 2);
    u16*   h1     = (u16*)carve((size_t)N * 128 * 2);
    u16*   hWb    = (u16*)carve((size_t)N * 128 * 2);
    float* aggf   = (float*)carve((size_t)N * 128 * 4);

    hipMemsetAsync(deg, 0, (size_t)N * 4, stream);
    hipMemsetAsync(cursor, 0, (size_t)N * 4, stream);
    hipMemsetAsync(stats, 0, 4 * 256 * 4, stream);
    hipMemsetAsync(ticket, 0, 4 * 4, stream);
    hipMemsetAsync(d_out, 0, (size_t)out_size * 4, stream);

    // graph preprocessing
    const int EB = (E + 255) / 256;
    const int NB = (N + 255) / 256;
    const int B = (N + 1023) / 1024;
    k_deg<<<EB, 256, 0, stream>>>(edst, E, deg);
    k_dinv<<<NB, 256, 0, stream>>>(deg, N, dinv);
    k_bsum<<<B, 256, 0, stream>>>(deg, N, bsum);
    k_scanb<<<1, 1, 0, stream>>>(bsum, B);
    k_offs<<<B, 256, 0, stream>>>(deg, N, bsum, offs);
    k_fill_edges<<<EB, 256, 0, stream>>>(esrc, edst, E, dinv, offs, cursor, csre);
    k_fill_self<<<NB, 256, 0, stream>>>(N, dinv, offs, cursor, csre);
    k_gcnt_bs<<<1, 128, 0, stream>>>(batch, N, gcnt);

    // weights -> bf16 transposed
    k_wt<128><<<1, 256, 0, stream>>>(W0, Wt0);
    k_wt<128><<<1, 256, 0, stream>>>(W1, Wt1);
    k_wt<128><<<1, 256, 0, stream>>>(W2, Wt2);
    k_wt<64><<<1, 256, 0, stream>>>(W3, Wt3);

    const float inv_n = 1.0f / (float)N;
    const int gemm_grid = (N + 63) / 64;
    const int chunk = (N + 255) / 256;
    const int n8_128 = N * 16;
    const int n8_64 = N * 8;

    // layer 0: x @ W0 (f32 in, cvt fused) -> agg -> stats+coef
    k_gemm_mfma<128, 1, false><<<gemm_grid, 256, 0, stream>>>(
        (const void*)x, nullptr, nullptr, nullptr, Wt0, nullptr, hWb, N);
    k_agg<128><<<2048, 256, 0, stream>>>(hWb, csre, offs, aggf, N);
    k_stats<128><<<1536, 256, 0, stream>>>(aggf, stats + 0, ticket + 0, g0, be0,
                                           coef + 0, inv_n, n8_128);
    // layer 1: GEMM fuses bnapply_0 (no skip), stores h0; -> agg -> stats+coef
    k_gemm_mfma<128, 2, true><<<gemm_grid, 256, 0, stream>>>(
        (const void*)aggf, nullptr, coef + 0, nullptr, Wt1, h0, hWb, N);
    k_agg<128><<<2048, 256, 0, stream>>>(hWb, csre, offs, aggf, N);
    k_stats<128><<<1536, 256, 0, stream>>>(aggf, stats + 256, ticket + 1, g1, be1,
                                           coef + 256, inv_n, n8_128);
    // layer 2: GEMM fuses bnapply_1 (skip from h0), stores h1; -> agg -> stats+coef
    k_gemm_mfma<128, 3, true><<<gemm_grid, 256, 0, stream>>>(
        (const void*)aggf, h0, coef + 256, swp, Wt2, h1, hWb, N);
    k_agg<128><<<2048, 256, 0, stream>>>(hWb, csre, offs, aggf, N);
    k_stats<128><<<1536, 256, 0, stream>>>(aggf, stats + 512, ticket + 2, g2, be2,
                                           coef + 512, inv_n, n8_128);
    // layer 3: GEMM fuses bnapply_2 (skip from h1, no store); -> agg -> stats+coef
    k_gemm_mfma<64, 3, false><<<gemm_grid, 256, 0, stream>>>(
        (const void*)aggf, h1, coef + 512, swp, Wt3, nullptr, hWb, N);
    k_agg<64><<<2048, 256, 0, stream>>>(hWb, csre, offs, aggf, N);
    k_stats<64><<<1536, 256, 0, stream>>>(aggf, stats + 768, ticket + 3, g3, be3,
                                          coef + 768, inv_n, n8_64);
    // BN + mean pool
    k_bnpool<<<256, 256, 0, stream>>>(aggf, batch, coef + 768, (float*)d_out, N, chunk);
    k_div<<<(out_size + 255) / 256, 256, 0, stream>>>((float*)d_out, gcnt, out_size);
}

// Round 13
// 777.341 us; speedup vs baseline: 2.6529x; 1.3894x over previous
//
#include <hip/hip_runtime.h>

// ---------------------------------------------------------------------------
// EnhancedGraphEncoder: 4-layer GCN + BN + ReLU + skip + global mean pool
// N=100000 nodes, E=1.6M edges (+self loops), dims 128->128->128->128->64.
// hW gather bf16; k_agg pure gather (stats evicted -> VGPR low -> occupancy
// high; R12 proved k_agg 237->~110us). k_stats: 256 blocks (was 1536 -> 393K
// same-address atomics = 120us of pure contention, the R12 top cost).
// BN+ReLU+skip fused in GEMMs; coef fused into k_stats last block (ticket).
// ---------------------------------------------------------------------------

typedef unsigned short u16;
typedef unsigned int u32;
typedef __attribute__((ext_vector_type(8))) short bf16x8;
typedef __attribute__((ext_vector_type(4))) float f32x4;

__device__ __forceinline__ float bflo(u32 u) { return __uint_as_float(u << 16); }
__device__ __forceinline__ float bfhi(u32 u) { return __uint_as_float(u & 0xffff0000u); }
__device__ __forceinline__ u16 f2bf(float f) {
    u32 u = __float_as_uint(f);
    u32 r = u + 0x7fffu + ((u >> 16) & 1u);   // round-to-nearest-even
    return (u16)(r >> 16);
}
__device__ __forceinline__ u32 pack2(float a, float b) {
    return (u32)f2bf(a) | ((u32)f2bf(b) << 16);
}

// ------------------------- preprocessing kernels ---------------------------

__global__ void k_deg(const int* __restrict__ edst, int E, int* __restrict__ deg) {
    int e = blockIdx.x * blockDim.x + threadIdx.x;
    if (e < E) atomicAdd(&deg[edst[e]], 1);
}

__global__ void k_dinv(const int* __restrict__ deg, int n, float* __restrict__ dinv) {
    int i = blockIdx.x * blockDim.x + threadIdx.x;
    if (i < n) {
        int c = deg[i] + 1;  // + self loop
        dinv[i] = rsqrtf((float)c);
    }
}

__global__ void k_bsum(const int* __restrict__ deg, int n, int* __restrict__ bsum) {
    __shared__ int sd[256];
    int base = blockIdx.x * 1024;
    int end = base + 1024; if (end > n) end = n;
    int s = 0;
    for (int i = base + threadIdx.x; i < end; i += 256) s += deg[i] + 1;
    sd[threadIdx.x] = s;
    __syncthreads();
    for (int off = 128; off > 0; off >>= 1) {
        if (threadIdx.x < off) sd[threadIdx.x] += sd[threadIdx.x + off];
        __syncthreads();
    }
    if (threadIdx.x == 0) bsum[blockIdx.x] = sd[0];
}

__global__ void k_scanb(int* __restrict__ bsum, int B) {
    int run = 0;
    for (int i = 0; i < B; ++i) { int v = bsum[i]; bsum[i] = run; run += v; }
}

__global__ void k_offs(const int* __restrict__ deg, int n, const int* __restrict__ bsum,
                       int* __restrict__ offs) {
    __shared__ int sd[256];
    int base = blockIdx.x * 1024;
    int carry = bsum[blockIdx.x];
    for (int tile = 0; tile < 4; ++tile) {
        int i = base + tile * 256 + threadIdx.x;
        int v = (i < n) ? (deg[i] + 1) : 0;
        sd[threadIdx.x] = v;
        __syncthreads();
        int x = v;
        for (int off = 1; off < 256; off <<= 1) {
            int y = (threadIdx.x >= off) ? sd[threadIdx.x - off] : 0;
            __syncthreads();
            x += y;
            sd[threadIdx.x] = x;
            __syncthreads();
        }
        if (i < n) offs[i] = carry + x - v;
        if (i == n - 1) offs[n] = carry + x;
        carry += sd[255];
        __syncthreads();
    }
}

__global__ void k_fill_edges(const int* __restrict__ esrc, const int* __restrict__ edst, int E,
                             const float* __restrict__ dinv, const int* __restrict__ offs,
                             int* __restrict__ cursor, uint2* __restrict__ csre) {
    int e = blockIdx.x * blockDim.x + threadIdx.x;
    if (e < E) {
        int s = esrc[e], d = edst[e];
        int slot = offs[d] + atomicAdd(&cursor[d], 1);
        csre[slot] = make_uint2((u32)s, __float_as_uint(dinv[s] * dinv[d]));
    }
}

__global__ void k_fill_self(int n, const float* __restrict__ dinv, const int* __restrict__ offs,
                            int* __restrict__ cursor, uint2* __restrict__ csre) {
    int i = blockIdx.x * blockDim.x + threadIdx.x;
    if (i < n) {
        int slot = offs[i] + atomicAdd(&cursor[i], 1);
        csre[slot] = make_uint2((u32)i, __float_as_uint(dinv[i] * dinv[i]));
    }
}

// batch is sorted -> per-graph counts via binary search, no atomics
__global__ void k_gcnt_bs(const int* __restrict__ batch, int n, int* __restrict__ gcnt) {
    int g = threadIdx.x;
    if (g < 128) {
        int lo0 = 0, hi0 = n;
        while (lo0 < hi0) { int m = (lo0 + hi0) >> 1; if (batch[m] < g) lo0 = m + 1; else hi0 = m; }
        int lo1 = lo0, hi1 = n;
        while (lo1 < hi1) { int m = (lo1 + hi1) >> 1; if (batch[m] < g + 1) lo1 = m + 1; else hi1 = m; }
        gcnt[g] = lo1 - lo0;
    }
}

// ------------------ weight transpose+convert: W[128][F] -> Wt[F][128] ------

template <int FOUT>
__global__ void k_wt(const float* __restrict__ W, u16* __restrict__ Wt) {
    __shared__ u16 l[128 * (FOUT + 8)];
    for (int i = threadIdx.x; i < 128 * FOUT; i += 256) {
        int k = i / FOUT, nn = i % FOUT;
        l[k * (FOUT + 8) + nn] = f2bf(W[i]);
    }
    __syncthreads();
    for (int i = threadIdx.x; i < 128 * FOUT; i += 256) {
        int nn = i >> 7, k = i & 127;
        Wt[nn * 128 + k] = l[k * (FOUT + 8) + nn];
    }
}

// ------------------------------- MFMA GEMM ---------------------------------
// O[n,FOUT](bf16) = A[n,128] @ W[128,FOUT], Wt[FOUT][128] bf16.
// MODE 1: A = f32 x, converted on the fly (layer 0).
// MODE 2: A = relu(aggf*sc+sh)      (fused BN, no skip)
// MODE 3: A = relu(aggf*sc+sh) + sw*hprev   (fused BN+skip)
// STOREH: additionally materialize A (bf16) to hout (later skip src).

template <int FOUT, int MODE, bool STOREH>
__global__ __launch_bounds__(256) void k_gemm_mfma(const void* __restrict__ Ap,
                                                   const u16* __restrict__ hprev,
                                                   const float* __restrict__ coef,
                                                   const float* __restrict__ swp,
                                                   const u16* __restrict__ Wt,
                                                   u16* __restrict__ hout,
                                                   u16* __restrict__ O, int n) {
    constexpr int NT = FOUT / 16;
    const int lane = threadIdx.x & 63;
    const int wave = threadIdx.x >> 6;
    const int fr = lane & 15;
    const int fq = lane >> 4;
    const int rowbase = blockIdx.x * 64 + wave * 16;
    const int arow = rowbase + fr;
    const bool aok = arow < n;
    const float* af = (const float*)Ap + (size_t)arow * 128 + fq * 8;
    const u16* hp = (MODE == 3) ? hprev + (size_t)arow * 128 + fq * 8 : nullptr;
    const u16* wp = Wt + fr * 128 + fq * 8;
    float sw = 0.f;
    if constexpr (MODE == 3) sw = *swp;

    f32x4 acc[NT];
#pragma unroll
    for (int t = 0; t < NT; ++t)
#pragma unroll
        for (int q = 0; q < 4; ++q) acc[t][q] = 0.f;

#pragma unroll
    for (int kk = 0; kk < 4; ++kk) {
        bf16x8 a;
#pragma unroll
        for (int q = 0; q < 8; ++q) a[q] = 0;
        if (aok) {
            if constexpr (MODE == 1) {
                const float4 x0 = *(const float4*)(af + kk * 32);
                const float4 x1 = *(const float4*)(af + kk * 32 + 4);
                a[0] = (short)f2bf(x0.x); a[1] = (short)f2bf(x0.y);
                a[2] = (short)f2bf(x0.z); a[3] = (short)f2bf(x0.w);
                a[4] = (short)f2bf(x1.x); a[5] = (short)f2bf(x1.y);
                a[6] = (short)f2bf(x1.z); a[7] = (short)f2bf(x1.w);
            } else {
                const int k0 = kk * 32 + fq * 8;
                const float4 v0 = *(const float4*)(af + kk * 32);
                const float4 v1 = *(const float4*)(af + kk * 32 + 4);
                const float4 sc0 = *(const float4*)&coef[k0];
                const float4 sc1 = *(const float4*)&coef[k0 + 4];
                const float4 sh0 = *(const float4*)&coef[128 + k0];
                const float4 sh1 = *(const float4*)&coef[128 + k0 + 4];
                float r[8];
                r[0] = fmaxf(fmaf(v0.x, sc0.x, sh0.x), 0.f);
                r[1] = fmaxf(fmaf(v0.y, sc0.y, sh0.y), 0.f);
                r[2] = fmaxf(fmaf(v0.z, sc0.z, sh0.z), 0.f);
                r[3] = fmaxf(fmaf(v0.w, sc0.w, sh0.w), 0.f);
                r[4] = fmaxf(fmaf(v1.x, sc1.x, sh1.x), 0.f);
                r[5] = fmaxf(fmaf(v1.y, sc1.y, sh1.y), 0.f);
                r[6] = fmaxf(fmaf(v1.z, sc1.z, sh1.z), 0.f);
                r[7] = fmaxf(fmaf(v1.w, sc1.w, sh1.w), 0.f);
                if constexpr (MODE == 3) {
                    const uint4 pv = *(const uint4*)(hp + kk * 32);
                    r[0] = fmaf(sw, bflo(pv.x), r[0]); r[1] = fmaf(sw, bfhi(pv.x), r[1]);
                    r[2] = fmaf(sw, bflo(pv.y), r[2]); r[3] = fmaf(sw, bfhi(pv.y), r[3]);
                    r[4] = fmaf(sw, bflo(pv.z), r[4]); r[5] = fmaf(sw, bfhi(pv.z), r[5]);
                    r[6] = fmaf(sw, bflo(pv.w), r[6]); r[7] = fmaf(sw, bfhi(pv.w), r[7]);
                }
                uint4 o;
                o.x = pack2(r[0], r[1]);
                o.y = pack2(r[2], r[3]);
                o.z = pack2(r[4], r[5]);
                o.w = pack2(r[6], r[7]);
                a = *(const bf16x8*)&o;
                if constexpr (STOREH)
                    *(uint4*)&hout[(size_t)arow * 128 + k0] = o;
            }
        }
#pragma unroll
        for (int t = 0; t < NT; ++t) {
            bf16x8 b = *(const bf16x8*)(wp + t * 16 * 128 + kk * 32);
            acc[t] = __builtin_amdgcn_mfma_f32_16x16x32_bf16(a, b, acc[t], 0, 0, 0);
        }
    }
#pragma unroll
    for (int i = 0; i < 4; ++i) {
        const int row = rowbase + fq * 4 + i;
        if (row < n) {
#pragma unroll
            for (int t = 0; t < NT; ++t)
                O[(size_t)row * FOUT + t * 16 + fr] = f2bf(acc[t][i]);
        }
    }
}

// ---------------------------- aggregation ----------------------------------
// agg[d,f](f32) = sum_{e: dst=d} hW[src_e, f](bf16) * norm_e  (CSR by dst)
// PURE gather: no BN stats -> low VGPR -> high occupancy (R12-proven).
// TPN=F/8 lanes per node, uint4 = 8 bf16 per lane, 8-deep edge unroll.

template <int F>
__global__ __launch_bounds__(256) void k_agg(const u16* __restrict__ hW,
                                             const uint2* __restrict__ csre,
                                             const int* __restrict__ offs,
                                             float* __restrict__ agg, int n) {
    constexpr int TPN = F / 8;       // lanes per node (16 or 8)
    constexpr int NPB = 256 / TPN;   // nodes per block (16 or 32)
    const int lane = threadIdx.x % TPN;
    const int sub = threadIdx.x / TPN;
    const int fbase = lane * 8;

    for (int node = blockIdx.x * NPB + sub; node < n; node += gridDim.x * NPB) {
        const int beg = offs[node];
        const int end = offs[node + 1];
        float4 b0 = make_float4(0.f, 0.f, 0.f, 0.f);
        float4 b1 = make_float4(0.f, 0.f, 0.f, 0.f);
        float4 c0 = make_float4(0.f, 0.f, 0.f, 0.f);
        float4 c1 = make_float4(0.f, 0.f, 0.f, 0.f);
        int j = beg;
        for (; j + 8 <= end; j += 8) {
            uint2 ei[8];
#pragma unroll
            for (int q = 0; q < 8; ++q) ei[q] = csre[j + q];
            uint4 v[8];
#pragma unroll
            for (int q = 0; q < 8; ++q)
                v[q] = *(const uint4*)&hW[(size_t)ei[q].x * F + fbase];
#pragma unroll
            for (int q = 0; q < 8; ++q) {
                const float w = __uint_as_float(ei[q].y);
                if (q & 1) {
                    c0.x = fmaf(bflo(v[q].x), w, c0.x); c0.y = fmaf(bfhi(v[q].x), w, c0.y);
                    c0.z = fmaf(bflo(v[q].y), w, c0.z); c0.w = fmaf(bfhi(v[q].y), w, c0.w);
                    c1.x = fmaf(bflo(v[q].z), w, c1.x); c1.y = fmaf(bfhi(v[q].z), w, c1.y);
                    c1.z = fmaf(bflo(v[q].w), w, c1.z); c1.w = fmaf(bfhi(v[q].w), w, c1.w);
                } else {
                    b0.x = fmaf(bflo(v[q].x), w, b0.x); b0.y = fmaf(bfhi(v[q].x), w, b0.y);
                    b0.z = fmaf(bflo(v[q].y), w, b0.z); b0.w = fmaf(bfhi(v[q].y), w, b0.w);
                    b1.x = fmaf(bflo(v[q].z), w, b1.x); b1.y = fmaf(bfhi(v[q].z), w, b1.y);
                    b1.z = fmaf(bflo(v[q].w), w, b1.z); b1.w = fmaf(bfhi(v[q].w), w, b1.w);
                }
            }
        }
        for (; j < end; ++j) {
            const uint2 e0 = csre[j];
            const float w = __uint_as_float(e0.y);
            const uint4 v0 = *(const uint4*)&hW[(size_t)e0.x * F + fbase];
            b0.x = fmaf(bflo(v0.x), w, b0.x); b0.y = fmaf(bfhi(v0.x), w, b0.y);
            b0.z = fmaf(bflo(v0.y), w, b0.z); b0.w = fmaf(bfhi(v0.y), w, b0.w);
            b1.x = fmaf(bflo(v0.z), w, b1.x); b1.y = fmaf(bfhi(v0.z), w, b1.y);
            b1.z = fmaf(bflo(v0.w), w, b1.z); b1.w = fmaf(bfhi(v0.w), w, b1.w);
        }
        b0.x += c0.x; b0.y += c0.y; b0.z += c0.z; b0.w += c0.w;
        b1.x += c1.x; b1.y += c1.y; b1.z += c1.z; b1.w += c1.w;
        __builtin_nontemporal_store(*(const f32x4*)&b0,
                                    (f32x4*)&agg[(size_t)node * F + fbase]);
        __builtin_nontemporal_store(*(const f32x4*)&b1,
                                    (f32x4*)&agg[(size_t)node * F + fbase + 4]);
    }
}

// --------------------- BN stats + coef (fused, ticketed) -------------------
// Streams aggf once with a SMALL grid (256 blocks -> 256 atomics/address,
// was 1536 -> contention-bound at 120us). Last block computes coef.

template <int F>
__global__ __launch_bounds__(256) void k_stats(const float* __restrict__ aggf,
                                               float* __restrict__ stats,
                                               int* __restrict__ ticket,
                                               const float* __restrict__ g,
                                               const float* __restrict__ be,
                                               float* __restrict__ coef,
                                               float inv_n, int n8) {
    constexpr int TPR = F / 8;
    const int tid0 = blockIdx.x * 256 + threadIdx.x;
    float s[8], q[8];
#pragma unroll
    for (int k = 0; k < 8; ++k) { s[k] = 0.f; q[k] = 0.f; }
    for (int i = tid0; i < n8; i += gridDim.x * 256) {
        const float4 v0 = *(const float4*)&aggf[(size_t)i * 8];
        const float4 v1 = *(const float4*)&aggf[(size_t)i * 8 + 4];
        s[0] += v0.x; s[1] += v0.y; s[2] += v0.z; s[3] += v0.w;
        s[4] += v1.x; s[5] += v1.y; s[6] += v1.z; s[7] += v1.w;
        q[0] = fmaf(v0.x, v0.x, q[0]); q[1] = fmaf(v0.y, v0.y, q[1]);
        q[2] = fmaf(v0.z, v0.z, q[2]); q[3] = fmaf(v0.w, v0.w, q[3]);
        q[4] = fmaf(v1.x, v1.x, q[4]); q[5] = fmaf(v1.y, v1.y, q[5]);
        q[6] = fmaf(v1.z, v1.z, q[6]); q[7] = fmaf(v1.w, v1.w, q[7]);
    }
    // lanes whose linear index differs only in bits >= log2(TPR) share fbase
#pragma unroll
    for (int m = TPR; m < 64; m <<= 1) {
#pragma unroll
        for (int k = 0; k < 8; ++k) {
            s[k] += __shfl_xor(s[k], m);
            q[k] += __shfl_xor(q[k], m);
        }
    }
    __shared__ float sred[2][4][TPR * 8];
    const int w = threadIdx.x >> 6;
    const int l64 = threadIdx.x & 63;
    if (l64 < TPR) {
#pragma unroll
        for (int k = 0; k < 8; ++k) {
            sred[0][w][l64 * 8 + k] = s[k];
            sred[1][w][l64 * 8 + k] = q[k];
        }
    }
    __syncthreads();
    if (threadIdx.x < TPR * 8) {
        float a = sred[0][0][threadIdx.x] + sred[0][1][threadIdx.x] +
                  sred[0][2][threadIdx.x] + sred[0][3][threadIdx.x];
        float b = sred[1][0][threadIdx.x] + sred[1][1][threadIdx.x] +
                  sred[1][2][threadIdx.x] + sred[1][3][threadIdx.x];
        // blockIdx*256*8 ≡ 0 (mod F) and wave base 64*8 ≡ 0 (mod F):
        // feature index is simply threadIdx.x
        const int ff = threadIdx.x & (F - 1);
        atomicAdd(&stats[ff], a);
        atomicAdd(&stats[F + ff], b);
    }
    __threadfence();
    __shared__ int last;
    if (threadIdx.x == 0) last = (atomicAdd(ticket, 1) == (int)gridDim.x - 1) ? 1 : 0;
    __syncthreads();
    if (last) {
        if (threadIdx.x < F) {
            const int f = threadIdx.x;
            float sum = atomicAdd(&stats[f], 0.f);        // coherent read
            float ssq = atomicAdd(&stats[F + f], 0.f);
            float mean = sum * inv_n;
            float var = fmaxf(ssq * inv_n - mean * mean, 0.f);
            float sc = g[f] * rsqrtf(var + 1e-5f);
            coef[f] = sc;
            coef[F + f] = be[f] - mean * sc;
        }
    }
}

// ----------------------- layer-3 BN + mean pool -----------------------------

__global__ __launch_bounds__(256) void k_bnpool(const float* __restrict__ C,
                                                const int* __restrict__ batch,
                                                const float* __restrict__ coef,
                                                float* __restrict__ out, int n,
                                                int chunk) {
    __shared__ float pool[128 * 64];
    for (int i = threadIdx.x; i < 128 * 64; i += 256) pool[i] = 0.f;
    __syncthreads();
    const int f = threadIdx.x & 63;
    const int sub = threadIdx.x >> 6;
    const float sc = coef[f];
    const float sh = coef[64 + f];
    const int lo = blockIdx.x * chunk;
    int hi = lo + chunk; if (hi > n) hi = n;
    for (int node = lo + sub; node < hi; node += 4) {
        float v = fmaf(sc, C[(size_t)node * 64 + f], sh);
        int g = batch[node];
        atomicAdd(&pool[g * 64 + f], v);
    }
    __syncthreads();
    for (int i = threadIdx.x; i < 128 * 64; i += 256) {
        float v = pool[i];
        if (v != 0.f) atomicAdd(&out[i], v);
    }
}

__global__ void k_div(float* __restrict__ out, const int* __restrict__ gcnt, int total) {
    int i = blockIdx.x * blockDim.x + threadIdx.x;
    if (i < total) {
        int g = i >> 6;
        int c = gcnt[g];
        if (c < 1) c = 1;
        out[i] = out[i] / (float)c;
    }
}

// ------------------------------ launcher ------------------------------------

static inline size_t align256(size_t x) { return (x + 255) & ~(size_t)255; }

extern "C" void kernel_launch(void* const* d_in, const int* in_sizes, int n_in,
                              void* d_out, int out_size, void* d_ws, size_t ws_size,
                              hipStream_t stream) {
    const float* x    = (const float*)d_in[0];
    const int* ei     = (const int*)d_in[1];
    const int* batch  = (const int*)d_in[2];
    const float* W0   = (const float*)d_in[3];
    const float* g0   = (const float*)d_in[5];
    const float* be0  = (const float*)d_in[6];
    const float* W1   = (const float*)d_in[7];
    const float* g1   = (const float*)d_in[9];
    const float* be1  = (const float*)d_in[10];
    const float* W2   = (const float*)d_in[11];
    const float* g2   = (const float*)d_in[13];
    const float* be2  = (const float*)d_in[14];
    const float* W3   = (const float*)d_in[15];
    const float* g3   = (const float*)d_in[17];
    const float* be3  = (const float*)d_in[18];
    const float* swp  = (const float*)d_in[19];

    const int N = in_sizes[0] / 128;
    const int E = in_sizes[1] / 2;
    const int T = E + N;
    const int* esrc = ei;
    const int* edst = ei + E;

    char* p = (char*)d_ws;
    auto carve = [&](size_t bytes) -> char* {
        char* r = p;
        p += align256(bytes);
        return r;
    };
    int*   deg    = (int*)carve((size_t)N * 4);
    float* dinv   = (float*)carve((size_t)N * 4);
    int*   offs   = (int*)carve((size_t)(N + 1) * 4);
    int*   cursor = (int*)carve((size_t)N * 4);
    int*   bsum   = (int*)carve(256 * 4);
    uint2* csre   = (uint2*)carve((size_t)T * 8);
    float* stats  = (float*)carve(4 * 256 * 4);
    float* coef   = (float*)carve(4 * 256 * 4);
    int*   ticket = (int*)carve(4 * 4);
    int*   gcnt   = (int*)carve(128 * 4);
    u16*   Wt0    = (u16*)carve(128 * 128 * 2);
    u16*   Wt1    = (u16*)carve(128 * 128 * 2);
    u16*   Wt2    = (u16*)carve(128 * 128 * 2);
    u16*   Wt3    = (u16*)carve(64 * 128 * 2);
    u16*   h0     = (u16*)carve((size_t)N * 128 * 2);
    u16*   h1     = (u16*)carve((size_t)N * 128 * 2);
    u16*   hWb    = (u16*)carve((size_t)N * 128 * 2);
    float* aggf   = (float*)carve((size_t)N * 128 * 4);

    hipMemsetAsync(deg, 0, (size_t)N * 4, stream);
    hipMemsetAsync(cursor, 0, (size_t)N * 4, stream);
    hipMemsetAsync(stats, 0, 4 * 256 * 4, stream);
    hipMemsetAsync(ticket, 0, 4 * 4, stream);
    hipMemsetAsync(d_out, 0, (size_t)out_size * 4, stream);

    // graph preprocessing
    const int EB = (E + 255) / 256;
    const int NB = (N + 255) / 256;
    const int B = (N + 1023) / 1024;
    k_deg<<<EB, 256, 0, stream>>>(edst, E, deg);
    k_dinv<<<NB, 256, 0, stream>>>(deg, N, dinv);
    k_bsum<<<B, 256, 0, stream>>>(deg, N, bsum);
    k_scanb<<<1, 1, 0, stream>>>(bsum, B);
    k_offs<<<B, 256, 0, stream>>>(deg, N, bsum, offs);
    k_fill_edges<<<EB, 256, 0, stream>>>(esrc, edst, E, dinv, offs, cursor, csre);
    k_fill_self<<<NB, 256, 0, stream>>>(N, dinv, offs, cursor, csre);
    k_gcnt_bs<<<1, 128, 0, stream>>>(batch, N, gcnt);

    // weights -> bf16 transposed
    k_wt<128><<<1, 256, 0, stream>>>(W0, Wt0);
    k_wt<128><<<1, 256, 0, stream>>>(W1, Wt1);
    k_wt<128><<<1, 256, 0, stream>>>(W2, Wt2);
    k_wt<64><<<1, 256, 0, stream>>>(W3, Wt3);

    const float inv_n = 1.0f / (float)N;
    const int gemm_grid = (N + 63) / 64;
    const int chunk = (N + 255) / 256;
    const int n8_128 = N * 16;
    const int n8_64 = N * 8;

    // layer 0: x @ W0 (f32 in, cvt fused) -> agg -> stats+coef
    k_gemm_mfma<128, 1, false><<<gemm_grid, 256, 0, stream>>>(
        (const void*)x, nullptr, nullptr, nullptr, Wt0, nullptr, hWb, N);
    k_agg<128><<<2048, 256, 0, stream>>>(hWb, csre, offs, aggf, N);
    k_stats<128><<<256, 256, 0, stream>>>(aggf, stats + 0, ticket + 0, g0, be0,
                                          coef + 0, inv_n, n8_128);
    // layer 1: GEMM fuses bnapply_0 (no skip), stores h0; -> agg -> stats+coef
    k_gemm_mfma<128, 2, true><<<gemm_grid, 256, 0, stream>>>(
        (const void*)aggf, nullptr, coef + 0, nullptr, Wt1, h0, hWb, N);
    k_agg<128><<<2048, 256, 0, stream>>>(hWb, csre, offs, aggf, N);
    k_stats<128><<<256, 256, 0, stream>>>(aggf, stats + 256, ticket + 1, g1, be1,
                                          coef + 256, inv_n, n8_128);
    // layer 2: GEMM fuses bnapply_1 (skip from h0), stores h1; -> agg -> stats+coef
    k_gemm_mfma<128, 3, true><<<gemm_grid, 256, 0, stream>>>(
        (const void*)aggf, h0, coef + 256, swp, Wt2, h1, hWb, N);
    k_agg<128><<<2048, 256, 0, stream>>>(hWb, csre, offs, aggf, N);
    k_stats<128><<<256, 256, 0, stream>>>(aggf, stats + 512, ticket + 2, g2, be2,
                                          coef + 512, inv_n, n8_128);
    // layer 3: GEMM fuses bnapply_2 (skip from h1, no store); -> agg -> stats+coef
    k_gemm_mfma<64, 3, false><<<gemm_grid, 256, 0, stream>>>(
        (const void*)aggf, h1, coef + 512, swp, Wt3, nullptr, hWb, N);
    k_agg<64><<<2048, 256, 0, stream>>>(hWb, csre, offs, aggf, N);
    k_stats<64><<<256, 256, 0, stream>>>(aggf, stats + 768, ticket + 3, g3, be3,
                                         coef + 768, inv_n, n8_64);
    // BN + mean pool
    k_bnpool<<<256, 256, 0, stream>>>(aggf, batch, coef + 768, (float*)d_out, N, chunk);
    k_div<<<(out_size + 255) / 256, 256, 0, stream>>>((float*)d_out, gcnt, out_size);
}